// Round 12
// baseline (288.114 us; speedup 1.0000x reference)
//
#include <hip/hip_runtime.h>
#include <math.h>
#include <stdint.h>

#define N_NODES 100000
#define N_EDGES 1600000
#define N_GRAPHS 64

// ---- atomic-free CSR build geometry ----
#define BSH 9                  // bucket width = 512 nodes
#define NBKT 196               // ceil(100000/512)
#define NCHUNK 256
#define EPC 6250               // N_EDGES / NCHUNK
#define FLAT (NBKT * NCHUNK)   // 50176

// ---------------- workspace layout (bytes) ----------------
// S(histMat)@ 0      : 50177 int
// row_ptr @ 400128   : 100001 int
// col     @ 800256   : 1600000 int (6.4 MB)
// pooled  @ 7200384  : 64*64 float
// gstart  @ 7216768  : 65 int
// M       @ 7217408  : 100000*64 fp32 (25.6 MB)  means / final h
//   pairs @ 7217408  : 1600000 int2 (12.8 MB) ALIASES M (dead before 1st agg)
// Hhi     @ 32817408 : 100000*64 bf16 (12.8 MB)
// Hlo     @ 45617408 : 100000*64 bf16 (12.8 MB)
// total ~58.4 MB

typedef __attribute__((ext_vector_type(8))) short bf16x8;
typedef __attribute__((ext_vector_type(8))) unsigned short u16x8;
typedef __attribute__((ext_vector_type(4))) float f32x4;

__device__ __forceinline__ void atomicMaxFloat(float* addr, float val) {
    if (val >= 0.0f) {
        atomicMax((int*)addr, __float_as_int(val));
    } else {
        atomicMin((unsigned int*)addr, __float_as_uint(val));
    }
}

__device__ __forceinline__ unsigned short f2bf(float f) {   // RNE fp32 -> bf16
    unsigned u = __float_as_uint(f);
    unsigned r = (u + 0x7FFFu + ((u >> 16) & 1u)) >> 16;
    return (unsigned short)r;
}
__device__ __forceinline__ float bf2f(unsigned short b) {
    return __uint_as_float(((unsigned)b) << 16);
}

__global__ void k_init(float* __restrict__ pooled) {
    int i = blockIdx.x * blockDim.x + threadIdx.x;
    if (i < N_GRAPHS * 64) pooled[i] = -INFINITY;
}

// ---- CSR phase 1: per-chunk coarse-bucket histogram (LDS atomics only) ----
__global__ __launch_bounds__(256) void k_rhist(const int* __restrict__ dst,
                                               int* __restrict__ S) {
    __shared__ int h[NBKT];
    for (int i = threadIdx.x; i < NBKT; i += 256) h[i] = 0;
    __syncthreads();
    int c = blockIdx.x;
    int e0 = c * EPC;
    for (int e = e0 + threadIdx.x; e < e0 + EPC; e += 256)
        atomicAdd(&h[dst[e] >> BSH], 1);
    __syncthreads();
    for (int i = threadIdx.x; i < NBKT; i += 256) S[i * NCHUNK + c] = h[i];
}

// ---- CSR phase 2: exclusive scan of S[0..FLAT) in place; S[FLAT]=total ----
__global__ __launch_bounds__(1024) void k_rscan(int* __restrict__ S) {
    __shared__ int part[1024];
    int t = threadIdx.x;
    const int seg = (FLAT + 1023) / 1024;   // 49
    int lo = t * seg;
    int hi = lo + seg; if (hi > FLAT) hi = FLAT;
    int s = 0;
    for (int i = lo; i < hi; ++i) s += S[i];
    part[t] = s;
    __syncthreads();
    for (int off = 1; off < 1024; off <<= 1) {
        int add = (t >= off) ? part[t - off] : 0;
        __syncthreads();
        part[t] += add;
        __syncthreads();
    }
    int ex = (t > 0) ? part[t - 1] : 0;
    if (t == 1023) S[FLAT] = part[1023];
    int run = ex;
    for (int i = lo; i < hi; ++i) { int v = S[i]; S[i] = run; run += v; }
}

// ---- CSR phase 3: scatter (src,dst) pairs bucket-grouped, no global atomics ----
__global__ __launch_bounds__(256) void k_rscatter(
    const int* __restrict__ src, const int* __restrict__ dst,
    const int* __restrict__ S, int2* __restrict__ pairs) {
    __shared__ int ofs[NBKT];
    __shared__ int cnt[NBKT];
    int c = blockIdx.x;
    for (int i = threadIdx.x; i < NBKT; i += 256) {
        ofs[i] = S[i * NCHUNK + c];
        cnt[i] = 0;
    }
    __syncthreads();
    int e0 = c * EPC;
    for (int e = e0 + threadIdx.x; e < e0 + EPC; e += 256) {
        int d = dst[e];
        int b = d >> BSH;
        int r = atomicAdd(&cnt[b], 1);           // LDS atomic
        pairs[ofs[b] + r] = make_int2(src[e], d);
    }
}

// ---- CSR phase 4: per bucket, build row_ptr + col (all LDS-local) ----
__global__ __launch_bounds__(256) void k_rbuild(
    const int2* __restrict__ pairs, const int* __restrict__ S,
    int* __restrict__ row_ptr, int* __restrict__ col) {
    __shared__ int ncnt[512];
    __shared__ int nofs[512];
    __shared__ int part[256];
    int b = blockIdx.x;
    int t = threadIdx.x;
    int base = S[b * NCHUNK];
    int next = (b == NBKT - 1) ? S[FLAT] : S[(b + 1) * NCHUNK];
    int count = next - base;
    int nodeBase = b << BSH;

    ncnt[2 * t] = 0; ncnt[2 * t + 1] = 0;
    __syncthreads();
    for (int i = t; i < count; i += 256)
        atomicAdd(&ncnt[pairs[base + i].y - nodeBase], 1);
    __syncthreads();
    // exclusive scan of ncnt[512]
    int v0 = ncnt[2 * t], v1 = ncnt[2 * t + 1];
    part[t] = v0 + v1;
    __syncthreads();
    for (int off = 1; off < 256; off <<= 1) {
        int add = (t >= off) ? part[t - off] : 0;
        __syncthreads();
        part[t] += add;
        __syncthreads();
    }
    int ex = (t > 0) ? part[t - 1] : 0;
    nofs[2 * t] = ex;
    nofs[2 * t + 1] = ex + v0;
    ncnt[2 * t] = 0; ncnt[2 * t + 1] = 0;
    __syncthreads();
    // row_ptr
    for (int i = t; i < 512; i += 256) {
        int node = nodeBase + i;
        if (node < N_NODES) row_ptr[node] = base + nofs[i];
    }
    if (b == 0 && t == 0) row_ptr[N_NODES] = N_EDGES;
    // col scatter (rank via LDS atomic; order within node irrelevant)
    for (int i = t; i < count; i += 256) {
        int2 p = pairs[base + i];
        int li = p.y - nodeBase;
        int r = atomicAdd(&ncnt[li], 1);
        col[base + nofs[li] + r] = p.x;
    }
}

// Convert input x (fp32, stride 32) -> bf16 hi plane (stride 32) for gathers.
__global__ void k_xcast(const float* __restrict__ x, unsigned short* __restrict__ xhi) {
    int i = blockIdx.x * blockDim.x + threadIdx.x;   // one u16x8 per thread
    int base = i * 8;
    if (base >= N_NODES * 32) return;
    const float4* xp = (const float4*)(x + base);
    float4 a = xp[0], b = xp[1];
    u16x8 o;
    o[0] = f2bf(a.x); o[1] = f2bf(a.y); o[2] = f2bf(a.z); o[3] = f2bf(a.w);
    o[4] = f2bf(b.x); o[5] = f2bf(b.y); o[6] = f2bf(b.z); o[7] = f2bf(b.w);
    *(u16x8*)(xhi + base) = o;
}

// ---------------------------------------------------------------------------
// Octo-gather aggregation: one 16B load instruction fetches G neighbor rows
// (G=8 for FIN=64, G=16 for FIN=32). lane group g = lane/LPR handles neighbor
// j+g; each lane loads u16x8 (8 features). Cross-group sum via shfl_xor.
// ---------------------------------------------------------------------------
#define NC 16

template <int FIN>
__global__ __launch_bounds__(256) void k_agg_bf(
    const unsigned short* __restrict__ hb,   // stride FIN
    const int* __restrict__ row_ptr, const int* __restrict__ col,
    float* __restrict__ mean) {
    int lane = threadIdx.x & 63;
    int wave = blockIdx.x * 4 + (threadIdx.x >> 6);
    int base = wave * NC;
    if (base >= N_NODES) return;
    int rp = row_ptr[base + (lane < NC ? lane : NC)];

    constexpr int G = (FIN == 64) ? 8 : 16;    // neighbor rows per load instr
    constexpr int LPR = 64 / G;                // lanes per row (8 or 4)
    int g  = lane / LPR;                       // neighbor sub-index
    int fq = lane % LPR;                       // feature-octet index

    for (int i = 0; i < NC; ++i) {
        int node = base + i;
        int start = __shfl(rp, i);
        int end   = __shfl(rp, i + 1);
        float s[8] = {};

        for (int eb = start; eb < end; eb += 64) {
            int n = end - eb; if (n > 64) n = 64;
            int c = (eb + lane < end) ? col[eb + lane] : 0;
            int j = 0;
            for (; j + 2 * G - 1 < n; j += 2 * G) {        // 2 loads in flight
                int cA = __shfl(c, j + g);
                int cB = __shfl(c, j + G + g);
                u16x8 vA = *(const u16x8*)(hb + (size_t)cA * FIN + fq * 8);
                u16x8 vB = *(const u16x8*)(hb + (size_t)cB * FIN + fq * 8);
#pragma unroll
                for (int q = 0; q < 8; ++q) s[q] += bf2f(vA[q]) + bf2f(vB[q]);
            }
            for (; j + G - 1 < n; j += G) {
                int cA = __shfl(c, j + g);
                u16x8 vA = *(const u16x8*)(hb + (size_t)cA * FIN + fq * 8);
#pragma unroll
                for (int q = 0; q < 8; ++q) s[q] += bf2f(vA[q]);
            }
            if (j < n) {                                    // masked tail
                int idx = j + g;
                bool valid = idx < n;
                int cA = __shfl(c, valid ? idx : 0);
                u16x8 vA = *(const u16x8*)(hb + (size_t)cA * FIN + fq * 8);
                if (valid) {
#pragma unroll
                    for (int q = 0; q < 8; ++q) s[q] += bf2f(vA[q]);
                }
            }
        }
        // cross-group reduction over the G neighbor sub-groups
#pragma unroll
        for (int m = LPR; m < 64; m <<= 1) {
#pragma unroll
            for (int q = 0; q < 8; ++q) s[q] += __shfl_xor(s[q], m);
        }
        int deg = end - start;
        float inv = (deg > 0) ? 1.0f / (float)deg : 0.0f;
        if (lane < LPR) {
            float* mp = mean + (size_t)node * 64 + fq * 8;
            *(float4*)(mp) = make_float4(s[0] * inv, s[1] * inv, s[2] * inv, s[3] * inv);
            *(float4*)(mp + 4) = make_float4(s[4] * inv, s[5] * inv, s[6] * inv, s[7] * inv);
        }
    }
}

// ---------------------------------------------------------------------------
// Dense transform via MFMA: out = mean @ Wl + bl + h @ Wr (hi/lo bf16 split)
// ---------------------------------------------------------------------------
template <int KM, bool XBF, int KX, int XS, bool OUTBF>
__global__ __launch_bounds__(256) void k_dense_mfma(
    const float* mean,                        // stride 64, may alias out
    const float* x,                           // fp32 path (XBF=false)
    const unsigned short* xhi, const unsigned short* xlo,  // bf16 path
    const float* __restrict__ Wl, const float* __restrict__ bl,
    const float* __restrict__ Wr,
    float* outf, unsigned short* ohi, unsigned short* olo) {
    int lane = threadIdx.x & 63;
    int strip = blockIdx.x * 4 + (threadIdx.x >> 6);
    if (strip * 16 >= N_NODES) return;
    int row0 = strip * 16;
    int m = lane & 15;
    int g = lane >> 4;

    f32x4 acc[4] = {};

    // ---- mean @ Wl (fp32 -> hi/lo split) ----
#pragma unroll
    for (int kt = 0; kt < KM / 32; ++kt) {
        int k0 = kt * 32 + g * 8;
        const float4* ap = (const float4*)(mean + (size_t)(row0 + m) * 64 + k0);
        float4 a0 = ap[0], a1 = ap[1];
        float av[8] = {a0.x, a0.y, a0.z, a0.w, a1.x, a1.y, a1.z, a1.w};
        bf16x8 ahi, alo;
#pragma unroll
        for (int j = 0; j < 8; ++j) {
            unsigned short hb = f2bf(av[j]);
            ahi[j] = (short)hb;
            alo[j] = (short)f2bf(av[j] - bf2f(hb));
        }
#pragma unroll
        for (int nt = 0; nt < 4; ++nt) {
            bf16x8 b;
#pragma unroll
            for (int j = 0; j < 8; ++j)
                b[j] = (short)f2bf(Wl[(size_t)(k0 + j) * 64 + nt * 16 + m]);
            acc[nt] = __builtin_amdgcn_mfma_f32_16x16x32_bf16(ahi, b, acc[nt], 0, 0, 0);
            acc[nt] = __builtin_amdgcn_mfma_f32_16x16x32_bf16(alo, b, acc[nt], 0, 0, 0);
        }
    }
    // ---- h @ Wr ----
#pragma unroll
    for (int kt = 0; kt < KX / 32; ++kt) {
        int k0 = kt * 32 + g * 8;
        bf16x8 ahi, alo;
        if constexpr (XBF) {
            ahi = *(const bf16x8*)(xhi + (size_t)(row0 + m) * XS + k0);
            alo = *(const bf16x8*)(xlo + (size_t)(row0 + m) * XS + k0);
        } else {
            const float4* ap = (const float4*)(x + (size_t)(row0 + m) * XS + k0);
            float4 a0 = ap[0], a1 = ap[1];
            float av[8] = {a0.x, a0.y, a0.z, a0.w, a1.x, a1.y, a1.z, a1.w};
#pragma unroll
            for (int j = 0; j < 8; ++j) {
                unsigned short hb = f2bf(av[j]);
                ahi[j] = (short)hb;
                alo[j] = (short)f2bf(av[j] - bf2f(hb));
            }
        }
#pragma unroll
        for (int nt = 0; nt < 4; ++nt) {
            bf16x8 b;
#pragma unroll
            for (int j = 0; j < 8; ++j)
                b[j] = (short)f2bf(Wr[(size_t)(k0 + j) * 64 + nt * 16 + m]);
            acc[nt] = __builtin_amdgcn_mfma_f32_16x16x32_bf16(ahi, b, acc[nt], 0, 0, 0);
            acc[nt] = __builtin_amdgcn_mfma_f32_16x16x32_bf16(alo, b, acc[nt], 0, 0, 0);
        }
    }
    // ---- bias + store ----
#pragma unroll
    for (int nt = 0; nt < 4; ++nt) {
        float bias = bl[nt * 16 + m];
#pragma unroll
        for (int r = 0; r < 4; ++r) {
            int row = row0 + g * 4 + r;
            float v = acc[nt][r] + bias;
            if constexpr (OUTBF) {
                unsigned short hb = f2bf(v);
                ohi[(size_t)row * 64 + nt * 16 + m] = hb;
                olo[(size_t)row * 64 + nt * 16 + m] = f2bf(v - bf2f(hb));
            } else {
                outf[(size_t)row * 64 + nt * 16 + m] = v;
            }
        }
    }
}

// ---- graph segment starts from the sorted batch vector ----
__global__ void k_gbound(const int* __restrict__ batch, int* __restrict__ gstart) {
    int i = blockIdx.x * blockDim.x + threadIdx.x;
    if (i >= N_NODES) return;
    int b = batch[i];
    if (i == 0) {
        for (int g = 0; g <= b; ++g) gstart[g] = 0;
    } else {
        int pb = batch[i - 1];
        for (int g = pb + 1; g <= b; ++g) gstart[g] = i;
    }
    if (i == N_NODES - 1) {
        for (int g = b + 1; g <= N_GRAPHS; ++g) gstart[g] = N_NODES;
    }
}

// ---- segment-parallel max pool: 8 splits x 64 graphs, 1 atomic/block/feat ----
#define PSPLIT 8
__global__ __launch_bounds__(256) void k_pool2(const float* __restrict__ h,
                                               const int* __restrict__ gstart,
                                               float* __restrict__ pooled) {
    __shared__ float red[4][64];
    int gr = blockIdx.x & 63;
    int split = blockIdx.x >> 6;
    int lane = threadIdx.x & 63;
    int w = threadIdx.x >> 6;
    int s = gstart[gr], e = gstart[gr + 1];
    float m = -INFINITY;
    for (int i = s + split * 4 + w; i < e; i += PSPLIT * 4)
        m = fmaxf(m, h[(size_t)i * 64 + lane]);
    red[w][lane] = m;
    __syncthreads();
    if (w == 0) {
        m = fmaxf(fmaxf(red[0][lane], red[1][lane]),
                  fmaxf(red[2][lane], red[3][lane]));
        if (m > -INFINITY) atomicMaxFloat(&pooled[gr * 64 + lane], m);
    }
}

__global__ void k_head(const float* __restrict__ pooled,
                       const float* __restrict__ Wout,
                       const float* __restrict__ bout, float* __restrict__ out) {
    int tid = threadIdx.x;          // 512 threads: g = tid>>3, o = tid&7
    int g = tid >> 3, o = tid & 7;
    float acc = bout[o];
#pragma unroll
    for (int k = 0; k < 64; ++k) acc += pooled[g * 64 + k] * Wout[k * 8 + o];
    float mx = acc;
#pragma unroll
    for (int m = 1; m < 8; m <<= 1) mx = fmaxf(mx, __shfl_xor(mx, m));
    float ex = expf(acc - mx);
    float sum = ex;
#pragma unroll
    for (int m = 1; m < 8; m <<= 1) sum += __shfl_xor(sum, m);
    out[g * 8 + o] = (acc - mx) - logf(sum);
}

extern "C" void kernel_launch(void* const* d_in, const int* in_sizes, int n_in,
                              void* d_out, int out_size, void* d_ws, size_t ws_size,
                              hipStream_t stream) {
    const float* x    = (const float*)d_in[0];
    const float* Wl0  = (const float*)d_in[1];
    const float* bl0  = (const float*)d_in[2];
    const float* Wr0  = (const float*)d_in[3];
    const float* Wl1  = (const float*)d_in[4];
    const float* bl1  = (const float*)d_in[5];
    const float* Wr1  = (const float*)d_in[6];
    const float* Wl2  = (const float*)d_in[7];
    const float* bl2  = (const float*)d_in[8];
    const float* Wr2  = (const float*)d_in[9];
    const float* Wout = (const float*)d_in[10];
    const float* bout = (const float*)d_in[11];
    const int*   eidx = (const int*)d_in[12];
    const int*   batch= (const int*)d_in[13];
    const int* src = eidx;
    const int* dst = eidx + N_EDGES;

    uint8_t* ws = (uint8_t*)d_ws;
    int*   S       = (int*)(ws + 0);                // 50177 ints
    int*   row_ptr = (int*)(ws + 400128);
    int*   col     = (int*)(ws + 800256);
    float* pooled  = (float*)(ws + 7200384);
    int*   gstart  = (int*)(ws + 7216768);
    float* M       = (float*)(ws + 7217408);
    int2*  pairs   = (int2*)(ws + 7217408);         // aliases M (dead before agg)
    unsigned short* Hhi = (unsigned short*)(ws + 32817408);
    unsigned short* Hlo = (unsigned short*)(ws + 45617408);

    k_init<<<16, 256, 0, stream>>>(pooled);
    k_rhist<<<NCHUNK, 256, 0, stream>>>(dst, S);
    k_rscan<<<1, 1024, 0, stream>>>(S);
    k_rscatter<<<NCHUNK, 256, 0, stream>>>(src, dst, S, pairs);
    k_rbuild<<<NBKT, 256, 0, stream>>>(pairs, S, row_ptr, col);
    k_xcast<<<(N_NODES * 32 / 8 + 255) / 256, 256, 0, stream>>>(x, Hhi);
    k_gbound<<<(N_NODES + 255) / 256, 256, 0, stream>>>(batch, gstart);

    int aggBlocks = (N_NODES / NC + 3) / 4;        // 1563
    int mfmaBlocks = (N_NODES / 16 + 3) / 4;       // 1563

    // layer 0: mean0 (from x-hi gathers) -> M; h1 -> Hhi/Hlo (overwrites x-hi)
    k_agg_bf<32><<<aggBlocks, 256, 0, stream>>>(Hhi, row_ptr, col, M);
    k_dense_mfma<32, false, 32, 32, true><<<mfmaBlocks, 256, 0, stream>>>(
        M, x, nullptr, nullptr, Wl0, bl0, Wr0, nullptr, Hhi, Hlo);
    // layer 1: mean1 (from h1-hi gathers) -> M; h2 -> Hhi/Hlo (in-place)
    k_agg_bf<64><<<aggBlocks, 256, 0, stream>>>(Hhi, row_ptr, col, M);
    k_dense_mfma<64, true, 64, 64, true><<<mfmaBlocks, 256, 0, stream>>>(
        M, nullptr, Hhi, Hlo, Wl1, bl1, Wr1, nullptr, Hhi, Hlo);
    // layer 2: mean2 -> M; h3 (fp32) -> M in-place; pool reads M
    k_agg_bf<64><<<aggBlocks, 256, 0, stream>>>(Hhi, row_ptr, col, M);
    k_dense_mfma<64, true, 64, 64, false><<<mfmaBlocks, 256, 0, stream>>>(
        M, nullptr, Hhi, Hlo, Wl2, bl2, Wr2, M, nullptr, nullptr);

    k_pool2<<<64 * PSPLIT, 256, 0, stream>>>(M, gstart, pooled);
    k_head<<<1, 512, 0, stream>>>(pooled, Wout, bout, (float*)d_out);
}

// Round 13
// 254.290 us; speedup vs baseline: 1.1330x; 1.1330x over previous
//
#include <hip/hip_runtime.h>
#include <math.h>
#include <stdint.h>

#define N_NODES 100000
#define N_EDGES 1600000
#define N_GRAPHS 64

// ---- atomic-free CSR build geometry ----
#define BSH 9                  // bucket width = 512 nodes
#define NBKT 196               // ceil(100000/512)
#define NCHUNK 256
#define EPC 6250               // N_EDGES / NCHUNK
#define FLAT (NBKT * NCHUNK)   // 50176

// ---------------- workspace layout (bytes) ----------------
// S(histMat)@ 0      : 50177 int
// row_ptr @ 400128   : 100001 int
// col     @ 800256   : 1600000 int (6.4 MB)
// pooled  @ 7200384  : 64*64 float
// gstart  @ 7216768  : 65 int
// M       @ 7217408  : 100000*64 fp32 (25.6 MB)  means / final h
//   pairs @ 7217408  : 1600000 int2 (12.8 MB) ALIASES M (dead before 1st agg)
// Hhi     @ 32817408 : 100000*64 bf16 (12.8 MB)
// Hlo     @ 45617408 : 100000*64 bf16 (12.8 MB)
// total ~58.4 MB

typedef __attribute__((ext_vector_type(8))) short bf16x8;
typedef __attribute__((ext_vector_type(8))) unsigned short u16x8;
typedef __attribute__((ext_vector_type(4))) float f32x4;

__device__ __forceinline__ void atomicMaxFloat(float* addr, float val) {
    if (val >= 0.0f) {
        atomicMax((int*)addr, __float_as_int(val));
    } else {
        atomicMin((unsigned int*)addr, __float_as_uint(val));
    }
}

__device__ __forceinline__ unsigned short f2bf(float f) {   // RNE fp32 -> bf16
    unsigned u = __float_as_uint(f);
    unsigned r = (u + 0x7FFFu + ((u >> 16) & 1u)) >> 16;
    return (unsigned short)r;
}
__device__ __forceinline__ float bf2f(unsigned short b) {
    return __uint_as_float(((unsigned)b) << 16);
}

__global__ void k_init(float* __restrict__ pooled) {
    int i = blockIdx.x * blockDim.x + threadIdx.x;
    if (i < N_GRAPHS * 64) pooled[i] = -INFINITY;
}

// ---- CSR phase 1: per-chunk coarse-bucket histogram (LDS atomics only) ----
__global__ __launch_bounds__(256) void k_rhist(const int* __restrict__ dst,
                                               int* __restrict__ S) {
    __shared__ int h[NBKT];
    for (int i = threadIdx.x; i < NBKT; i += 256) h[i] = 0;
    __syncthreads();
    int c = blockIdx.x;
    int e0 = c * EPC;
    for (int e = e0 + threadIdx.x; e < e0 + EPC; e += 256)
        atomicAdd(&h[dst[e] >> BSH], 1);
    __syncthreads();
    for (int i = threadIdx.x; i < NBKT; i += 256) S[i * NCHUNK + c] = h[i];
}

// ---- CSR phase 2: exclusive scan of S[0..FLAT) in place; S[FLAT]=total ----
__global__ __launch_bounds__(1024) void k_rscan(int* __restrict__ S) {
    __shared__ int part[1024];
    int t = threadIdx.x;
    const int seg = (FLAT + 1023) / 1024;   // 49
    int lo = t * seg;
    int hi = lo + seg; if (hi > FLAT) hi = FLAT;
    int s = 0;
    for (int i = lo; i < hi; ++i) s += S[i];
    part[t] = s;
    __syncthreads();
    for (int off = 1; off < 1024; off <<= 1) {
        int add = (t >= off) ? part[t - off] : 0;
        __syncthreads();
        part[t] += add;
        __syncthreads();
    }
    int ex = (t > 0) ? part[t - 1] : 0;
    if (t == 1023) S[FLAT] = part[1023];
    int run = ex;
    for (int i = lo; i < hi; ++i) { int v = S[i]; S[i] = run; run += v; }
}

// ---- CSR phase 3: scatter (src,dst) pairs bucket-grouped, no global atomics ----
__global__ __launch_bounds__(256) void k_rscatter(
    const int* __restrict__ src, const int* __restrict__ dst,
    const int* __restrict__ S, int2* __restrict__ pairs) {
    __shared__ int ofs[NBKT];
    __shared__ int cnt[NBKT];
    int c = blockIdx.x;
    for (int i = threadIdx.x; i < NBKT; i += 256) {
        ofs[i] = S[i * NCHUNK + c];
        cnt[i] = 0;
    }
    __syncthreads();
    int e0 = c * EPC;
    for (int e = e0 + threadIdx.x; e < e0 + EPC; e += 256) {
        int d = dst[e];
        int b = d >> BSH;
        int r = atomicAdd(&cnt[b], 1);           // LDS atomic
        pairs[ofs[b] + r] = make_int2(src[e], d);
    }
}

// ---- CSR phase 4: per bucket, build row_ptr + col (all LDS-local) ----
__global__ __launch_bounds__(256) void k_rbuild(
    const int2* __restrict__ pairs, const int* __restrict__ S,
    int* __restrict__ row_ptr, int* __restrict__ col) {
    __shared__ int ncnt[512];
    __shared__ int nofs[512];
    __shared__ int part[256];
    int b = blockIdx.x;
    int t = threadIdx.x;
    int base = S[b * NCHUNK];
    int next = (b == NBKT - 1) ? S[FLAT] : S[(b + 1) * NCHUNK];
    int count = next - base;
    int nodeBase = b << BSH;

    ncnt[2 * t] = 0; ncnt[2 * t + 1] = 0;
    __syncthreads();
    for (int i = t; i < count; i += 256)
        atomicAdd(&ncnt[pairs[base + i].y - nodeBase], 1);
    __syncthreads();
    // exclusive scan of ncnt[512]
    int v0 = ncnt[2 * t], v1 = ncnt[2 * t + 1];
    part[t] = v0 + v1;
    __syncthreads();
    for (int off = 1; off < 256; off <<= 1) {
        int add = (t >= off) ? part[t - off] : 0;
        __syncthreads();
        part[t] += add;
        __syncthreads();
    }
    int ex = (t > 0) ? part[t - 1] : 0;
    nofs[2 * t] = ex;
    nofs[2 * t + 1] = ex + v0;
    ncnt[2 * t] = 0; ncnt[2 * t + 1] = 0;
    __syncthreads();
    // row_ptr
    for (int i = t; i < 512; i += 256) {
        int node = nodeBase + i;
        if (node < N_NODES) row_ptr[node] = base + nofs[i];
    }
    if (b == 0 && t == 0) row_ptr[N_NODES] = N_EDGES;
    // col scatter (rank via LDS atomic; order within node irrelevant)
    for (int i = t; i < count; i += 256) {
        int2 p = pairs[base + i];
        int li = p.y - nodeBase;
        int r = atomicAdd(&ncnt[li], 1);
        col[base + nofs[li] + r] = p.x;
    }
}

// Convert input x (fp32, stride 32) -> bf16 hi plane (stride 32) for gathers.
__global__ void k_xcast(const float* __restrict__ x, unsigned short* __restrict__ xhi) {
    int i = blockIdx.x * blockDim.x + threadIdx.x;   // one u16x8 per thread
    int base = i * 8;
    if (base >= N_NODES * 32) return;
    const float4* xp = (const float4*)(x + base);
    float4 a = xp[0], b = xp[1];
    u16x8 o;
    o[0] = f2bf(a.x); o[1] = f2bf(a.y); o[2] = f2bf(a.z); o[3] = f2bf(a.w);
    o[4] = f2bf(b.x); o[5] = f2bf(b.y); o[6] = f2bf(b.z); o[7] = f2bf(b.w);
    *(u16x8*)(xhi + base) = o;
}

// ---------------------------------------------------------------------------
// Quad-gather aggregation (reverted to R11 config — R12's 16B/G=16 variant
// regressed: occupancy 52->42%, wider accumulators, 16-way scatter loads).
// G=4 rows/load (FIN=64), G=8 (FIN=32); 8B ushort4 per lane. NC=8 so the
// grid launches 12504 waves (~8/SIMD) instead of 6250 (~6/SIMD, the R11
// occupancy ceiling). 4 loads in flight for deg>=16.
// ---------------------------------------------------------------------------
#define NC 8

template <int FIN>
__global__ __launch_bounds__(256) void k_agg_bf(
    const unsigned short* __restrict__ hb,   // stride FIN
    const int* __restrict__ row_ptr, const int* __restrict__ col,
    float* __restrict__ mean) {
    int lane = threadIdx.x & 63;
    int wave = blockIdx.x * 4 + (threadIdx.x >> 6);
    int base = wave * NC;
    if (base >= N_NODES) return;
    int rp = row_ptr[base + (lane < NC ? lane : NC)];

    constexpr int G = (FIN == 64) ? 4 : 8;     // neighbor rows per load instr
    constexpr int LPR = 64 / G;                // lanes per row (16 or 8)
    int g  = lane / LPR;                       // neighbor sub-index
    int fq = lane % LPR;                       // feature quad index

    for (int i = 0; i < NC; ++i) {
        int node = base + i;
        int start = __shfl(rp, i);
        int end   = __shfl(rp, i + 1);
        float s0 = 0.0f, s1 = 0.0f, s2 = 0.0f, s3 = 0.0f;

        for (int eb = start; eb < end; eb += 64) {
            int n = end - eb; if (n > 64) n = 64;
            int c = (eb + lane < end) ? col[eb + lane] : 0;
            int j = 0;
            for (; j + 4 * G - 1 < n; j += 4 * G) {        // 4 loads in flight
                int cA = __shfl(c, j + g);
                int cB = __shfl(c, j + G + g);
                int cC = __shfl(c, j + 2 * G + g);
                int cD = __shfl(c, j + 3 * G + g);
                ushort4 vA = *(const ushort4*)(hb + (size_t)cA * FIN + fq * 4);
                ushort4 vB = *(const ushort4*)(hb + (size_t)cB * FIN + fq * 4);
                ushort4 vC = *(const ushort4*)(hb + (size_t)cC * FIN + fq * 4);
                ushort4 vD = *(const ushort4*)(hb + (size_t)cD * FIN + fq * 4);
                s0 += (bf2f(vA.x) + bf2f(vB.x)) + (bf2f(vC.x) + bf2f(vD.x));
                s1 += (bf2f(vA.y) + bf2f(vB.y)) + (bf2f(vC.y) + bf2f(vD.y));
                s2 += (bf2f(vA.z) + bf2f(vB.z)) + (bf2f(vC.z) + bf2f(vD.z));
                s3 += (bf2f(vA.w) + bf2f(vB.w)) + (bf2f(vC.w) + bf2f(vD.w));
            }
            for (; j + 2 * G - 1 < n; j += 2 * G) {        // 2 loads in flight
                int cA = __shfl(c, j + g);
                int cB = __shfl(c, j + G + g);
                ushort4 vA = *(const ushort4*)(hb + (size_t)cA * FIN + fq * 4);
                ushort4 vB = *(const ushort4*)(hb + (size_t)cB * FIN + fq * 4);
                s0 += bf2f(vA.x) + bf2f(vB.x);
                s1 += bf2f(vA.y) + bf2f(vB.y);
                s2 += bf2f(vA.z) + bf2f(vB.z);
                s3 += bf2f(vA.w) + bf2f(vB.w);
            }
            for (; j + G - 1 < n; j += G) {
                int cA = __shfl(c, j + g);
                ushort4 vA = *(const ushort4*)(hb + (size_t)cA * FIN + fq * 4);
                s0 += bf2f(vA.x);
                s1 += bf2f(vA.y);
                s2 += bf2f(vA.z);
                s3 += bf2f(vA.w);
            }
            if (j < n) {                                    // masked tail
                int idx = j + g;
                bool valid = idx < n;
                int cA = __shfl(c, valid ? idx : 0);
                ushort4 vA = *(const ushort4*)(hb + (size_t)cA * FIN + fq * 4);
                if (valid) {
                    s0 += bf2f(vA.x);
                    s1 += bf2f(vA.y);
                    s2 += bf2f(vA.z);
                    s3 += bf2f(vA.w);
                }
            }
        }
        // cross-group reduction: sum over the G neighbor sub-groups
#pragma unroll
        for (int m = LPR; m < 64; m <<= 1) {
            s0 += __shfl_xor(s0, m);
            s1 += __shfl_xor(s1, m);
            s2 += __shfl_xor(s2, m);
            s3 += __shfl_xor(s3, m);
        }
        int deg = end - start;
        float inv = (deg > 0) ? 1.0f / (float)deg : 0.0f;
        if (lane < LPR) {
            *(float4*)(mean + (size_t)node * 64 + fq * 4) =
                make_float4(s0 * inv, s1 * inv, s2 * inv, s3 * inv);
        }
    }
}

// ---------------------------------------------------------------------------
// Dense transform via MFMA: out = mean @ Wl + bl + h @ Wr (hi/lo bf16 split)
// ---------------------------------------------------------------------------
template <int KM, bool XBF, int KX, int XS, bool OUTBF>
__global__ __launch_bounds__(256) void k_dense_mfma(
    const float* mean,                        // stride 64, may alias out
    const float* x,                           // fp32 path (XBF=false)
    const unsigned short* xhi, const unsigned short* xlo,  // bf16 path
    const float* __restrict__ Wl, const float* __restrict__ bl,
    const float* __restrict__ Wr,
    float* outf, unsigned short* ohi, unsigned short* olo) {
    int lane = threadIdx.x & 63;
    int strip = blockIdx.x * 4 + (threadIdx.x >> 6);
    if (strip * 16 >= N_NODES) return;
    int row0 = strip * 16;
    int m = lane & 15;
    int g = lane >> 4;

    f32x4 acc[4] = {};

    // ---- mean @ Wl (fp32 -> hi/lo split) ----
#pragma unroll
    for (int kt = 0; kt < KM / 32; ++kt) {
        int k0 = kt * 32 + g * 8;
        const float4* ap = (const float4*)(mean + (size_t)(row0 + m) * 64 + k0);
        float4 a0 = ap[0], a1 = ap[1];
        float av[8] = {a0.x, a0.y, a0.z, a0.w, a1.x, a1.y, a1.z, a1.w};
        bf16x8 ahi, alo;
#pragma unroll
        for (int j = 0; j < 8; ++j) {
            unsigned short hb = f2bf(av[j]);
            ahi[j] = (short)hb;
            alo[j] = (short)f2bf(av[j] - bf2f(hb));
        }
#pragma unroll
        for (int nt = 0; nt < 4; ++nt) {
            bf16x8 b;
#pragma unroll
            for (int j = 0; j < 8; ++j)
                b[j] = (short)f2bf(Wl[(size_t)(k0 + j) * 64 + nt * 16 + m]);
            acc[nt] = __builtin_amdgcn_mfma_f32_16x16x32_bf16(ahi, b, acc[nt], 0, 0, 0);
            acc[nt] = __builtin_amdgcn_mfma_f32_16x16x32_bf16(alo, b, acc[nt], 0, 0, 0);
        }
    }
    // ---- h @ Wr ----
#pragma unroll
    for (int kt = 0; kt < KX / 32; ++kt) {
        int k0 = kt * 32 + g * 8;
        bf16x8 ahi, alo;
        if constexpr (XBF) {
            ahi = *(const bf16x8*)(xhi + (size_t)(row0 + m) * XS + k0);
            alo = *(const bf16x8*)(xlo + (size_t)(row0 + m) * XS + k0);
        } else {
            const float4* ap = (const float4*)(x + (size_t)(row0 + m) * XS + k0);
            float4 a0 = ap[0], a1 = ap[1];
            float av[8] = {a0.x, a0.y, a0.z, a0.w, a1.x, a1.y, a1.z, a1.w};
#pragma unroll
            for (int j = 0; j < 8; ++j) {
                unsigned short hb = f2bf(av[j]);
                ahi[j] = (short)hb;
                alo[j] = (short)f2bf(av[j] - bf2f(hb));
            }
        }
#pragma unroll
        for (int nt = 0; nt < 4; ++nt) {
            bf16x8 b;
#pragma unroll
            for (int j = 0; j < 8; ++j)
                b[j] = (short)f2bf(Wr[(size_t)(k0 + j) * 64 + nt * 16 + m]);
            acc[nt] = __builtin_amdgcn_mfma_f32_16x16x32_bf16(ahi, b, acc[nt], 0, 0, 0);
            acc[nt] = __builtin_amdgcn_mfma_f32_16x16x32_bf16(alo, b, acc[nt], 0, 0, 0);
        }
    }
    // ---- bias + store ----
#pragma unroll
    for (int nt = 0; nt < 4; ++nt) {
        float bias = bl[nt * 16 + m];
#pragma unroll
        for (int r = 0; r < 4; ++r) {
            int row = row0 + g * 4 + r;
            float v = acc[nt][r] + bias;
            if constexpr (OUTBF) {
                unsigned short hb = f2bf(v);
                ohi[(size_t)row * 64 + nt * 16 + m] = hb;
                olo[(size_t)row * 64 + nt * 16 + m] = f2bf(v - bf2f(hb));
            } else {
                outf[(size_t)row * 64 + nt * 16 + m] = v;
            }
        }
    }
}

// ---- graph segment starts from the sorted batch vector ----
__global__ void k_gbound(const int* __restrict__ batch, int* __restrict__ gstart) {
    int i = blockIdx.x * blockDim.x + threadIdx.x;
    if (i >= N_NODES) return;
    int b = batch[i];
    if (i == 0) {
        for (int g = 0; g <= b; ++g) gstart[g] = 0;
    } else {
        int pb = batch[i - 1];
        for (int g = pb + 1; g <= b; ++g) gstart[g] = i;
    }
    if (i == N_NODES - 1) {
        for (int g = b + 1; g <= N_GRAPHS; ++g) gstart[g] = N_NODES;
    }
}

// ---- segment-parallel max pool: 8 splits x 64 graphs, 1 atomic/block/feat ----
#define PSPLIT 8
__global__ __launch_bounds__(256) void k_pool2(const float* __restrict__ h,
                                               const int* __restrict__ gstart,
                                               float* __restrict__ pooled) {
    __shared__ float red[4][64];
    int gr = blockIdx.x & 63;
    int split = blockIdx.x >> 6;
    int lane = threadIdx.x & 63;
    int w = threadIdx.x >> 6;
    int s = gstart[gr], e = gstart[gr + 1];
    float m = -INFINITY;
    for (int i = s + split * 4 + w; i < e; i += PSPLIT * 4)
        m = fmaxf(m, h[(size_t)i * 64 + lane]);
    red[w][lane] = m;
    __syncthreads();
    if (w == 0) {
        m = fmaxf(fmaxf(red[0][lane], red[1][lane]),
                  fmaxf(red[2][lane], red[3][lane]));
        if (m > -INFINITY) atomicMaxFloat(&pooled[gr * 64 + lane], m);
    }
}

__global__ void k_head(const float* __restrict__ pooled,
                       const float* __restrict__ Wout,
                       const float* __restrict__ bout, float* __restrict__ out) {
    int tid = threadIdx.x;          // 512 threads: g = tid>>3, o = tid&7
    int g = tid >> 3, o = tid & 7;
    float acc = bout[o];
#pragma unroll
    for (int k = 0; k < 64; ++k) acc += pooled[g * 64 + k] * Wout[k * 8 + o];
    float mx = acc;
#pragma unroll
    for (int m = 1; m < 8; m <<= 1) mx = fmaxf(mx, __shfl_xor(mx, m));
    float ex = expf(acc - mx);
    float sum = ex;
#pragma unroll
    for (int m = 1; m < 8; m <<= 1) sum += __shfl_xor(sum, m);
    out[g * 8 + o] = (acc - mx) - logf(sum);
}

extern "C" void kernel_launch(void* const* d_in, const int* in_sizes, int n_in,
                              void* d_out, int out_size, void* d_ws, size_t ws_size,
                              hipStream_t stream) {
    const float* x    = (const float*)d_in[0];
    const float* Wl0  = (const float*)d_in[1];
    const float* bl0  = (const float*)d_in[2];
    const float* Wr0  = (const float*)d_in[3];
    const float* Wl1  = (const float*)d_in[4];
    const float* bl1  = (const float*)d_in[5];
    const float* Wr1  = (const float*)d_in[6];
    const float* Wl2  = (const float*)d_in[7];
    const float* bl2  = (const float*)d_in[8];
    const float* Wr2  = (const float*)d_in[9];
    const float* Wout = (const float*)d_in[10];
    const float* bout = (const float*)d_in[11];
    const int*   eidx = (const int*)d_in[12];
    const int*   batch= (const int*)d_in[13];
    const int* src = eidx;
    const int* dst = eidx + N_EDGES;

    uint8_t* ws = (uint8_t*)d_ws;
    int*   S       = (int*)(ws + 0);                // 50177 ints
    int*   row_ptr = (int*)(ws + 400128);
    int*   col     = (int*)(ws + 800256);
    float* pooled  = (float*)(ws + 7200384);
    int*   gstart  = (int*)(ws + 7216768);
    float* M       = (float*)(ws + 7217408);
    int2*  pairs   = (int2*)(ws + 7217408);         // aliases M (dead before agg)
    unsigned short* Hhi = (unsigned short*)(ws + 32817408);
    unsigned short* Hlo = (unsigned short*)(ws + 45617408);

    k_init<<<16, 256, 0, stream>>>(pooled);
    k_rhist<<<NCHUNK, 256, 0, stream>>>(dst, S);
    k_rscan<<<1, 1024, 0, stream>>>(S);
    k_rscatter<<<NCHUNK, 256, 0, stream>>>(src, dst, S, pairs);
    k_rbuild<<<NBKT, 256, 0, stream>>>(pairs, S, row_ptr, col);
    k_xcast<<<(N_NODES * 32 / 8 + 255) / 256, 256, 0, stream>>>(x, Hhi);
    k_gbound<<<(N_NODES + 255) / 256, 256, 0, stream>>>(batch, gstart);

    int aggBlocks = (N_NODES / NC + 3) / 4;        // 3126
    int mfmaBlocks = (N_NODES / 16 + 3) / 4;       // 1563

    // layer 0: mean0 (from x-hi gathers) -> M; h1 -> Hhi/Hlo (overwrites x-hi)
    k_agg_bf<32><<<aggBlocks, 256, 0, stream>>>(Hhi, row_ptr, col, M);
    k_dense_mfma<32, false, 32, 32, true><<<mfmaBlocks, 256, 0, stream>>>(
        M, x, nullptr, nullptr, Wl0, bl0, Wr0, nullptr, Hhi, Hlo);
    // layer 1: mean1 (from h1-hi gathers) -> M; h2 -> Hhi/Hlo (in-place)
    k_agg_bf<64><<<aggBlocks, 256, 0, stream>>>(Hhi, row_ptr, col, M);
    k_dense_mfma<64, true, 64, 64, true><<<mfmaBlocks, 256, 0, stream>>>(
        M, nullptr, Hhi, Hlo, Wl1, bl1, Wr1, nullptr, Hhi, Hlo);
    // layer 2: mean2 -> M; h3 (fp32) -> M in-place; pool reads M
    k_agg_bf<64><<<aggBlocks, 256, 0, stream>>>(Hhi, row_ptr, col, M);
    k_dense_mfma<64, true, 64, 64, false><<<mfmaBlocks, 256, 0, stream>>>(
        M, nullptr, Hhi, Hlo, Wl2, bl2, Wr2, M, nullptr, nullptr);

    k_pool2<<<64 * PSPLIT, 256, 0, stream>>>(M, gstart, pooled);
    k_head<<<1, 512, 0, stream>>>(pooled, Wout, bout, (float*)d_out);
}

// Round 14
// 247.559 us; speedup vs baseline: 1.1638x; 1.0272x over previous
//
#include <hip/hip_runtime.h>
#include <math.h>
#include <stdint.h>

#define N_NODES 100000
#define N_EDGES 1600000
#define N_GRAPHS 64

// ---- atomic-free CSR build geometry ----
#define BSH 9                  // bucket width = 512 nodes
#define NBKT 196               // ceil(100000/512)
#define NCHUNK 256
#define EPC 6250               // N_EDGES / NCHUNK
#define FLAT (NBKT * NCHUNK)   // 50176

// ---------------- workspace layout (bytes) ----------------
// S(histMat)@ 0      : 50177 int
// row_ptr @ 400128   : 100001 int
// col     @ 800256   : 1600000 int (6.4 MB)
// pooled  @ 7200384  : 64*64 float
// gstart  @ 7216768  : 65 int
// M       @ 7217408  : 100000*64 fp32 (25.6 MB)  means
//   pairs @ 7217408  : 1600000 uint (6.4 MB) ALIASES M (dead before 1st agg)
// Hhi     @ 32817408 : 100000*64 bf16 (12.8 MB)
// Hlo     @ 45617408 : 100000*64 bf16 (12.8 MB)
// total ~58.4 MB

typedef __attribute__((ext_vector_type(8))) short bf16x8;
typedef __attribute__((ext_vector_type(8))) unsigned short u16x8;
typedef __attribute__((ext_vector_type(4))) float f32x4;

__device__ __forceinline__ void atomicMaxFloat(float* addr, float val) {
    if (val >= 0.0f) {
        atomicMax((int*)addr, __float_as_int(val));
    } else {
        atomicMin((unsigned int*)addr, __float_as_uint(val));
    }
}

__device__ __forceinline__ unsigned short f2bf(float f) {   // RNE fp32 -> bf16
    unsigned u = __float_as_uint(f);
    unsigned r = (u + 0x7FFFu + ((u >> 16) & 1u)) >> 16;
    return (unsigned short)r;
}
__device__ __forceinline__ float bf2f(unsigned short b) {
    return __uint_as_float(((unsigned)b) << 16);
}

// ---- fused prep: xcast (400000 octets) + gbound + pooled init ----
__global__ __launch_bounds__(256) void k_prep(
    const float* __restrict__ x, unsigned short* __restrict__ xhi,
    const int* __restrict__ batch, int* __restrict__ gstart,
    float* __restrict__ pooled) {
    int i = blockIdx.x * blockDim.x + threadIdx.x;
    if (i < N_NODES * 32 / 8) {
        int base = i * 8;
        const float4* xp = (const float4*)(x + base);
        float4 a = xp[0], b = xp[1];
        u16x8 o;
        o[0] = f2bf(a.x); o[1] = f2bf(a.y); o[2] = f2bf(a.z); o[3] = f2bf(a.w);
        o[4] = f2bf(b.x); o[5] = f2bf(b.y); o[6] = f2bf(b.z); o[7] = f2bf(b.w);
        *(u16x8*)(xhi + base) = o;
    }
    if (i < N_GRAPHS * 64) pooled[i] = -INFINITY;
    if (i < N_NODES) {
        int b = batch[i];
        if (i == 0) {
            for (int g = 0; g <= b; ++g) gstart[g] = 0;
        } else {
            int pb = batch[i - 1];
            for (int g = pb + 1; g <= b; ++g) gstart[g] = i;
        }
        if (i == N_NODES - 1) {
            for (int g = b + 1; g <= N_GRAPHS; ++g) gstart[g] = N_NODES;
        }
    }
}

// ---- CSR phase 1: per-chunk coarse-bucket histogram (LDS atomics only) ----
__global__ __launch_bounds__(256) void k_rhist(const int* __restrict__ dst,
                                               int* __restrict__ S) {
    __shared__ int h[NBKT];
    for (int i = threadIdx.x; i < NBKT; i += 256) h[i] = 0;
    __syncthreads();
    int c = blockIdx.x;
    int e0 = c * EPC;
    for (int e = e0 + threadIdx.x; e < e0 + EPC; e += 256)
        atomicAdd(&h[dst[e] >> BSH], 1);
    __syncthreads();
    for (int i = threadIdx.x; i < NBKT; i += 256) S[i * NCHUNK + c] = h[i];
}

// ---- CSR phase 2: exclusive scan of S[0..FLAT) in place; S[FLAT]=total ----
__global__ __launch_bounds__(1024) void k_rscan(int* __restrict__ S) {
    __shared__ int part[1024];
    int t = threadIdx.x;
    const int seg = (FLAT + 1023) / 1024;   // 49
    int lo = t * seg;
    int hi = lo + seg; if (hi > FLAT) hi = FLAT;
    int s = 0;
    for (int i = lo; i < hi; ++i) s += S[i];
    part[t] = s;
    __syncthreads();
    for (int off = 1; off < 1024; off <<= 1) {
        int add = (t >= off) ? part[t - off] : 0;
        __syncthreads();
        part[t] += add;
        __syncthreads();
    }
    int ex = (t > 0) ? part[t - 1] : 0;
    if (t == 1023) S[FLAT] = part[1023];
    int run = ex;
    for (int i = lo; i < hi; ++i) { int v = S[i]; S[i] = run; run += v; }
}

// ---- CSR phase 3: scatter packed (dstLocal:9 | src:17) bucket-grouped ----
__global__ __launch_bounds__(256) void k_rscatter(
    const int* __restrict__ src, const int* __restrict__ dst,
    const int* __restrict__ S, unsigned int* __restrict__ pairs) {
    __shared__ int ofs[NBKT];
    __shared__ int cnt[NBKT];
    int c = blockIdx.x;
    for (int i = threadIdx.x; i < NBKT; i += 256) {
        ofs[i] = S[i * NCHUNK + c];
        cnt[i] = 0;
    }
    __syncthreads();
    int e0 = c * EPC;
    for (int e = e0 + threadIdx.x; e < e0 + EPC; e += 256) {
        int d = dst[e];
        int b = d >> BSH;
        int r = atomicAdd(&cnt[b], 1);           // LDS atomic
        pairs[ofs[b] + r] = ((unsigned)(d & 511) << 17) | (unsigned)src[e];
    }
}

// ---- CSR phase 4: per bucket, build row_ptr + col (all LDS-local) ----
__global__ __launch_bounds__(256) void k_rbuild(
    const unsigned int* __restrict__ pairs, const int* __restrict__ S,
    int* __restrict__ row_ptr, int* __restrict__ col) {
    __shared__ int ncnt[512];
    __shared__ int nofs[512];
    __shared__ int part[256];
    int b = blockIdx.x;
    int t = threadIdx.x;
    int base = S[b * NCHUNK];
    int next = (b == NBKT - 1) ? S[FLAT] : S[(b + 1) * NCHUNK];
    int count = next - base;
    int nodeBase = b << BSH;

    ncnt[2 * t] = 0; ncnt[2 * t + 1] = 0;
    __syncthreads();
    for (int i = t; i < count; i += 256)
        atomicAdd(&ncnt[pairs[base + i] >> 17], 1);
    __syncthreads();
    // exclusive scan of ncnt[512]
    int v0 = ncnt[2 * t], v1 = ncnt[2 * t + 1];
    part[t] = v0 + v1;
    __syncthreads();
    for (int off = 1; off < 256; off <<= 1) {
        int add = (t >= off) ? part[t - off] : 0;
        __syncthreads();
        part[t] += add;
        __syncthreads();
    }
    int ex = (t > 0) ? part[t - 1] : 0;
    nofs[2 * t] = ex;
    nofs[2 * t + 1] = ex + v0;
    ncnt[2 * t] = 0; ncnt[2 * t + 1] = 0;
    __syncthreads();
    // row_ptr
    for (int i = t; i < 512; i += 256) {
        int node = nodeBase + i;
        if (node < N_NODES) row_ptr[node] = base + nofs[i];
    }
    if (b == 0 && t == 0) row_ptr[N_NODES] = N_EDGES;
    // col scatter (rank via LDS atomic; order within node irrelevant)
    for (int i = t; i < count; i += 256) {
        unsigned p = pairs[base + i];
        int li = p >> 17;
        int r = atomicAdd(&ncnt[li], 1);
        col[base + nofs[li] + r] = (int)(p & 0x1FFFFu);
    }
}

// ---------------------------------------------------------------------------
// Quad-gather aggregation (R13 config: G=4/FIN=64, G=8/FIN=32; NC=8).
// ---------------------------------------------------------------------------
#define NC 8

template <int FIN>
__global__ __launch_bounds__(256) void k_agg_bf(
    const unsigned short* __restrict__ hb,   // stride FIN
    const int* __restrict__ row_ptr, const int* __restrict__ col,
    float* __restrict__ mean) {
    int lane = threadIdx.x & 63;
    int wave = blockIdx.x * 4 + (threadIdx.x >> 6);
    int base = wave * NC;
    if (base >= N_NODES) return;
    int rp = row_ptr[base + (lane < NC ? lane : NC)];

    constexpr int G = (FIN == 64) ? 4 : 8;     // neighbor rows per load instr
    constexpr int LPR = 64 / G;                // lanes per row (16 or 8)
    int g  = lane / LPR;                       // neighbor sub-index
    int fq = lane % LPR;                       // feature quad index

    for (int i = 0; i < NC; ++i) {
        int node = base + i;
        int start = __shfl(rp, i);
        int end   = __shfl(rp, i + 1);
        float s0 = 0.0f, s1 = 0.0f, s2 = 0.0f, s3 = 0.0f;

        for (int eb = start; eb < end; eb += 64) {
            int n = end - eb; if (n > 64) n = 64;
            int c = (eb + lane < end) ? col[eb + lane] : 0;
            int j = 0;
            for (; j + 4 * G - 1 < n; j += 4 * G) {        // 4 loads in flight
                int cA = __shfl(c, j + g);
                int cB = __shfl(c, j + G + g);
                int cC = __shfl(c, j + 2 * G + g);
                int cD = __shfl(c, j + 3 * G + g);
                ushort4 vA = *(const ushort4*)(hb + (size_t)cA * FIN + fq * 4);
                ushort4 vB = *(const ushort4*)(hb + (size_t)cB * FIN + fq * 4);
                ushort4 vC = *(const ushort4*)(hb + (size_t)cC * FIN + fq * 4);
                ushort4 vD = *(const ushort4*)(hb + (size_t)cD * FIN + fq * 4);
                s0 += (bf2f(vA.x) + bf2f(vB.x)) + (bf2f(vC.x) + bf2f(vD.x));
                s1 += (bf2f(vA.y) + bf2f(vB.y)) + (bf2f(vC.y) + bf2f(vD.y));
                s2 += (bf2f(vA.z) + bf2f(vB.z)) + (bf2f(vC.z) + bf2f(vD.z));
                s3 += (bf2f(vA.w) + bf2f(vB.w)) + (bf2f(vC.w) + bf2f(vD.w));
            }
            for (; j + 2 * G - 1 < n; j += 2 * G) {        // 2 loads in flight
                int cA = __shfl(c, j + g);
                int cB = __shfl(c, j + G + g);
                ushort4 vA = *(const ushort4*)(hb + (size_t)cA * FIN + fq * 4);
                ushort4 vB = *(const ushort4*)(hb + (size_t)cB * FIN + fq * 4);
                s0 += bf2f(vA.x) + bf2f(vB.x);
                s1 += bf2f(vA.y) + bf2f(vB.y);
                s2 += bf2f(vA.z) + bf2f(vB.z);
                s3 += bf2f(vA.w) + bf2f(vB.w);
            }
            for (; j + G - 1 < n; j += G) {
                int cA = __shfl(c, j + g);
                ushort4 vA = *(const ushort4*)(hb + (size_t)cA * FIN + fq * 4);
                s0 += bf2f(vA.x);
                s1 += bf2f(vA.y);
                s2 += bf2f(vA.z);
                s3 += bf2f(vA.w);
            }
            if (j < n) {                                    // masked tail
                int idx = j + g;
                bool valid = idx < n;
                int cA = __shfl(c, valid ? idx : 0);
                ushort4 vA = *(const ushort4*)(hb + (size_t)cA * FIN + fq * 4);
                if (valid) {
                    s0 += bf2f(vA.x);
                    s1 += bf2f(vA.y);
                    s2 += bf2f(vA.z);
                    s3 += bf2f(vA.w);
                }
            }
        }
        // cross-group reduction: sum over the G neighbor sub-groups
#pragma unroll
        for (int m = LPR; m < 64; m <<= 1) {
            s0 += __shfl_xor(s0, m);
            s1 += __shfl_xor(s1, m);
            s2 += __shfl_xor(s2, m);
            s3 += __shfl_xor(s3, m);
        }
        int deg = end - start;
        float inv = (deg > 0) ? 1.0f / (float)deg : 0.0f;
        if (lane < LPR) {
            *(float4*)(mean + (size_t)node * 64 + fq * 4) =
                make_float4(s0 * inv, s1 * inv, s2 * inv, s3 * inv);
        }
    }
}

// ---------------------------------------------------------------------------
// Dense transform via MFMA: out = mean @ Wl + bl + h @ Wr (hi/lo bf16 split)
// OM: 0 = fp32 out, 1 = bf16 hi+lo planes, 2 = bf16 hi plane only (pre-pool)
// ---------------------------------------------------------------------------
template <int KM, bool XBF, int KX, int XS, int OM>
__global__ __launch_bounds__(256) void k_dense_mfma(
    const float* mean,                        // stride 64, may alias out
    const float* x,                           // fp32 path (XBF=false)
    const unsigned short* xhi, const unsigned short* xlo,  // bf16 path
    const float* __restrict__ Wl, const float* __restrict__ bl,
    const float* __restrict__ Wr,
    float* outf, unsigned short* ohi, unsigned short* olo) {
    int lane = threadIdx.x & 63;
    int strip = blockIdx.x * 4 + (threadIdx.x >> 6);
    if (strip * 16 >= N_NODES) return;
    int row0 = strip * 16;
    int m = lane & 15;
    int g = lane >> 4;

    f32x4 acc[4] = {};

    // ---- mean @ Wl (fp32 -> hi/lo split) ----
#pragma unroll
    for (int kt = 0; kt < KM / 32; ++kt) {
        int k0 = kt * 32 + g * 8;
        const float4* ap = (const float4*)(mean + (size_t)(row0 + m) * 64 + k0);
        float4 a0 = ap[0], a1 = ap[1];
        float av[8] = {a0.x, a0.y, a0.z, a0.w, a1.x, a1.y, a1.z, a1.w};
        bf16x8 ahi, alo;
#pragma unroll
        for (int j = 0; j < 8; ++j) {
            unsigned short hb = f2bf(av[j]);
            ahi[j] = (short)hb;
            alo[j] = (short)f2bf(av[j] - bf2f(hb));
        }
#pragma unroll
        for (int nt = 0; nt < 4; ++nt) {
            bf16x8 b;
#pragma unroll
            for (int j = 0; j < 8; ++j)
                b[j] = (short)f2bf(Wl[(size_t)(k0 + j) * 64 + nt * 16 + m]);
            acc[nt] = __builtin_amdgcn_mfma_f32_16x16x32_bf16(ahi, b, acc[nt], 0, 0, 0);
            acc[nt] = __builtin_amdgcn_mfma_f32_16x16x32_bf16(alo, b, acc[nt], 0, 0, 0);
        }
    }
    // ---- h @ Wr ----
#pragma unroll
    for (int kt = 0; kt < KX / 32; ++kt) {
        int k0 = kt * 32 + g * 8;
        bf16x8 ahi, alo;
        if constexpr (XBF) {
            ahi = *(const bf16x8*)(xhi + (size_t)(row0 + m) * XS + k0);
            alo = *(const bf16x8*)(xlo + (size_t)(row0 + m) * XS + k0);
        } else {
            const float4* ap = (const float4*)(x + (size_t)(row0 + m) * XS + k0);
            float4 a0 = ap[0], a1 = ap[1];
            float av[8] = {a0.x, a0.y, a0.z, a0.w, a1.x, a1.y, a1.z, a1.w};
#pragma unroll
            for (int j = 0; j < 8; ++j) {
                unsigned short hb = f2bf(av[j]);
                ahi[j] = (short)hb;
                alo[j] = (short)f2bf(av[j] - bf2f(hb));
            }
        }
#pragma unroll
        for (int nt = 0; nt < 4; ++nt) {
            bf16x8 b;
#pragma unroll
            for (int j = 0; j < 8; ++j)
                b[j] = (short)f2bf(Wr[(size_t)(k0 + j) * 64 + nt * 16 + m]);
            acc[nt] = __builtin_amdgcn_mfma_f32_16x16x32_bf16(ahi, b, acc[nt], 0, 0, 0);
            acc[nt] = __builtin_amdgcn_mfma_f32_16x16x32_bf16(alo, b, acc[nt], 0, 0, 0);
        }
    }
    // ---- bias + store ----
#pragma unroll
    for (int nt = 0; nt < 4; ++nt) {
        float bias = bl[nt * 16 + m];
#pragma unroll
        for (int r = 0; r < 4; ++r) {
            int row = row0 + g * 4 + r;
            float v = acc[nt][r] + bias;
            if constexpr (OM == 1) {
                unsigned short hb = f2bf(v);
                ohi[(size_t)row * 64 + nt * 16 + m] = hb;
                olo[(size_t)row * 64 + nt * 16 + m] = f2bf(v - bf2f(hb));
            } else if constexpr (OM == 2) {
                ohi[(size_t)row * 64 + nt * 16 + m] = f2bf(v);
            } else {
                outf[(size_t)row * 64 + nt * 16 + m] = v;
            }
        }
    }
}

// ---- segment-parallel max pool over the bf16 hi plane ----
#define PSPLIT 8
__global__ __launch_bounds__(256) void k_pool2(const unsigned short* __restrict__ h,
                                               const int* __restrict__ gstart,
                                               float* __restrict__ pooled) {
    __shared__ float red[4][64];
    int gr = blockIdx.x & 63;
    int split = blockIdx.x >> 6;
    int lane = threadIdx.x & 63;
    int w = threadIdx.x >> 6;
    int s = gstart[gr], e = gstart[gr + 1];
    float m = -INFINITY;
    for (int i = s + split * 4 + w; i < e; i += PSPLIT * 4)
        m = fmaxf(m, bf2f(h[(size_t)i * 64 + lane]));
    red[w][lane] = m;
    __syncthreads();
    if (w == 0) {
        m = fmaxf(fmaxf(red[0][lane], red[1][lane]),
                  fmaxf(red[2][lane], red[3][lane]));
        if (m > -INFINITY) atomicMaxFloat(&pooled[gr * 64 + lane], m);
    }
}

__global__ void k_head(const float* __restrict__ pooled,
                       const float* __restrict__ Wout,
                       const float* __restrict__ bout, float* __restrict__ out) {
    int tid = threadIdx.x;          // 512 threads: g = tid>>3, o = tid&7
    int g = tid >> 3, o = tid & 7;
    float acc = bout[o];
#pragma unroll
    for (int k = 0; k < 64; ++k) acc += pooled[g * 64 + k] * Wout[k * 8 + o];
    float mx = acc;
#pragma unroll
    for (int m = 1; m < 8; m <<= 1) mx = fmaxf(mx, __shfl_xor(mx, m));
    float ex = expf(acc - mx);
    float sum = ex;
#pragma unroll
    for (int m = 1; m < 8; m <<= 1) sum += __shfl_xor(sum, m);
    out[g * 8 + o] = (acc - mx) - logf(sum);
}

extern "C" void kernel_launch(void* const* d_in, const int* in_sizes, int n_in,
                              void* d_out, int out_size, void* d_ws, size_t ws_size,
                              hipStream_t stream) {
    const float* x    = (const float*)d_in[0];
    const float* Wl0  = (const float*)d_in[1];
    const float* bl0  = (const float*)d_in[2];
    const float* Wr0  = (const float*)d_in[3];
    const float* Wl1  = (const float*)d_in[4];
    const float* bl1  = (const float*)d_in[5];
    const float* Wr1  = (const float*)d_in[6];
    const float* Wl2  = (const float*)d_in[7];
    const float* bl2  = (const float*)d_in[8];
    const float* Wr2  = (const float*)d_in[9];
    const float* Wout = (const float*)d_in[10];
    const float* bout = (const float*)d_in[11];
    const int*   eidx = (const int*)d_in[12];
    const int*   batch= (const int*)d_in[13];
    const int* src = eidx;
    const int* dst = eidx + N_EDGES;

    uint8_t* ws = (uint8_t*)d_ws;
    int*   S       = (int*)(ws + 0);                // 50177 ints
    int*   row_ptr = (int*)(ws + 400128);
    int*   col     = (int*)(ws + 800256);
    float* pooled  = (float*)(ws + 7200384);
    int*   gstart  = (int*)(ws + 7216768);
    float* M       = (float*)(ws + 7217408);
    unsigned int* pairs = (unsigned int*)(ws + 7217408);  // aliases M
    unsigned short* Hhi = (unsigned short*)(ws + 32817408);
    unsigned short* Hlo = (unsigned short*)(ws + 45617408);

    k_prep<<<(N_NODES * 32 / 8 + 255) / 256, 256, 0, stream>>>(
        x, Hhi, batch, gstart, pooled);
    k_rhist<<<NCHUNK, 256, 0, stream>>>(dst, S);
    k_rscan<<<1, 1024, 0, stream>>>(S);
    k_rscatter<<<NCHUNK, 256, 0, stream>>>(src, dst, S, pairs);
    k_rbuild<<<NBKT, 256, 0, stream>>>(pairs, S, row_ptr, col);

    int aggBlocks = (N_NODES / NC + 3) / 4;        // 3126
    int mfmaBlocks = (N_NODES / 16 + 3) / 4;       // 1563

    // layer 0: mean0 (from x-hi gathers) -> M; h1 -> Hhi/Hlo (overwrites x-hi)
    k_agg_bf<32><<<aggBlocks, 256, 0, stream>>>(Hhi, row_ptr, col, M);
    k_dense_mfma<32, false, 32, 32, 1><<<mfmaBlocks, 256, 0, stream>>>(
        M, x, nullptr, nullptr, Wl0, bl0, Wr0, nullptr, Hhi, Hlo);
    // layer 1: mean1 (from h1-hi gathers) -> M; h2 -> Hhi/Hlo (in-place)
    k_agg_bf<64><<<aggBlocks, 256, 0, stream>>>(Hhi, row_ptr, col, M);
    k_dense_mfma<64, true, 64, 64, 1><<<mfmaBlocks, 256, 0, stream>>>(
        M, nullptr, Hhi, Hlo, Wl1, bl1, Wr1, nullptr, Hhi, Hlo);
    // layer 2: mean2 -> M; h3 -> Hhi (bf16-hi only, in-place); pool reads Hhi
    k_agg_bf<64><<<aggBlocks, 256, 0, stream>>>(Hhi, row_ptr, col, M);
    k_dense_mfma<64, true, 64, 64, 2><<<mfmaBlocks, 256, 0, stream>>>(
        M, nullptr, Hhi, Hlo, Wl2, bl2, Wr2, nullptr, Hhi, nullptr);

    k_pool2<<<64 * PSPLIT, 256, 0, stream>>>(Hhi, gstart, pooled);
    k_head<<<1, 512, 0, stream>>>(pooled, Wout, bout, (float*)d_out);
}

// Round 15
// 238.380 us; speedup vs baseline: 1.2086x; 1.0385x over previous
//
#include <hip/hip_runtime.h>
#include <math.h>
#include <stdint.h>

#define N_NODES 100000
#define N_EDGES 1600000
#define N_GRAPHS 64

// ---- atomic-free CSR build geometry ----
#define BSH 9                  // bucket width = 512 nodes
#define NBKT 196               // ceil(100000/512)
#define NCHUNK 256
#define EPC 6250               // N_EDGES / NCHUNK
#define FLAT (NBKT * NCHUNK)   // 50176

// ---------------- workspace layout (bytes) ----------------
// S(histMat)@ 0      : 50177 int
// row_ptr @ 400128   : 100001 int
// col     @ 800256   : 1600000 int (6.4 MB)
// pooled  @ 7200384  : 64*64 float
// gstart  @ 7216768  : 65 int
// H1hi    @ 7217408  : 100000*64 bf16 (12.8 MB)
// H1lo    @ 20017408 : 100000*64 bf16 (12.8 MB)
// H2hi    @ 32817408 : 100000*64 bf16 (12.8 MB)   [pairs 6.4MB aliases: dead after rbuild]
// H2lo    @ 45617408 : 100000*64 bf16 (12.8 MB)   [Xhi 6.4MB aliases: dead after layer-0]
// total ~58.4 MB.  M buffer eliminated (means live in LDS inside fused kernel).

typedef __attribute__((ext_vector_type(8))) short bf16x8;
typedef __attribute__((ext_vector_type(8))) unsigned short u16x8;
typedef __attribute__((ext_vector_type(4))) float f32x4;

__device__ __forceinline__ void atomicMaxFloat(float* addr, float val) {
    if (val >= 0.0f) {
        atomicMax((int*)addr, __float_as_int(val));
    } else {
        atomicMin((unsigned int*)addr, __float_as_uint(val));
    }
}

__device__ __forceinline__ unsigned short f2bf(float f) {   // RNE fp32 -> bf16
    unsigned u = __float_as_uint(f);
    unsigned r = (u + 0x7FFFu + ((u >> 16) & 1u)) >> 16;
    return (unsigned short)r;
}
__device__ __forceinline__ float bf2f(unsigned short b) {
    return __uint_as_float(((unsigned)b) << 16);
}

// ---- fused prep: xcast (400000 octets) + gbound + pooled init ----
__global__ __launch_bounds__(256) void k_prep(
    const float* __restrict__ x, unsigned short* __restrict__ xhi,
    const int* __restrict__ batch, int* __restrict__ gstart,
    float* __restrict__ pooled) {
    int i = blockIdx.x * blockDim.x + threadIdx.x;
    if (i < N_NODES * 32 / 8) {
        int base = i * 8;
        const float4* xp = (const float4*)(x + base);
        float4 a = xp[0], b = xp[1];
        u16x8 o;
        o[0] = f2bf(a.x); o[1] = f2bf(a.y); o[2] = f2bf(a.z); o[3] = f2bf(a.w);
        o[4] = f2bf(b.x); o[5] = f2bf(b.y); o[6] = f2bf(b.z); o[7] = f2bf(b.w);
        *(u16x8*)(xhi + base) = o;
    }
    if (i < N_GRAPHS * 64) pooled[i] = -INFINITY;
    if (i < N_NODES) {
        int b = batch[i];
        if (i == 0) {
            for (int g = 0; g <= b; ++g) gstart[g] = 0;
        } else {
            int pb = batch[i - 1];
            for (int g = pb + 1; g <= b; ++g) gstart[g] = i;
        }
        if (i == N_NODES - 1) {
            for (int g = b + 1; g <= N_GRAPHS; ++g) gstart[g] = N_NODES;
        }
    }
}

// ---- CSR phase 1: per-chunk coarse-bucket histogram (LDS atomics only) ----
__global__ __launch_bounds__(256) void k_rhist(const int* __restrict__ dst,
                                               int* __restrict__ S) {
    __shared__ int h[NBKT];
    for (int i = threadIdx.x; i < NBKT; i += 256) h[i] = 0;
    __syncthreads();
    int c = blockIdx.x;
    int e0 = c * EPC;
    for (int e = e0 + threadIdx.x; e < e0 + EPC; e += 256)
        atomicAdd(&h[dst[e] >> BSH], 1);
    __syncthreads();
    for (int i = threadIdx.x; i < NBKT; i += 256) S[i * NCHUNK + c] = h[i];
}

// ---- CSR phase 2: exclusive scan of S[0..FLAT) in place; S[FLAT]=total ----
__global__ __launch_bounds__(1024) void k_rscan(int* __restrict__ S) {
    __shared__ int part[1024];
    int t = threadIdx.x;
    const int seg = (FLAT + 1023) / 1024;   // 49
    int lo = t * seg;
    int hi = lo + seg; if (hi > FLAT) hi = FLAT;
    int s = 0;
    for (int i = lo; i < hi; ++i) s += S[i];
    part[t] = s;
    __syncthreads();
    for (int off = 1; off < 1024; off <<= 1) {
        int add = (t >= off) ? part[t - off] : 0;
        __syncthreads();
        part[t] += add;
        __syncthreads();
    }
    int ex = (t > 0) ? part[t - 1] : 0;
    if (t == 1023) S[FLAT] = part[1023];
    int run = ex;
    for (int i = lo; i < hi; ++i) { int v = S[i]; S[i] = run; run += v; }
}

// ---- CSR phase 3: scatter packed (dstLocal:9 | src:17) bucket-grouped ----
__global__ __launch_bounds__(256) void k_rscatter(
    const int* __restrict__ src, const int* __restrict__ dst,
    const int* __restrict__ S, unsigned int* __restrict__ pairs) {
    __shared__ int ofs[NBKT];
    __shared__ int cnt[NBKT];
    int c = blockIdx.x;
    for (int i = threadIdx.x; i < NBKT; i += 256) {
        ofs[i] = S[i * NCHUNK + c];
        cnt[i] = 0;
    }
    __syncthreads();
    int e0 = c * EPC;
    for (int e = e0 + threadIdx.x; e < e0 + EPC; e += 256) {
        int d = dst[e];
        int b = d >> BSH;
        int r = atomicAdd(&cnt[b], 1);           // LDS atomic
        pairs[ofs[b] + r] = ((unsigned)(d & 511) << 17) | (unsigned)src[e];
    }
}

// ---- CSR phase 4: per bucket, build row_ptr + col (all LDS-local) ----
__global__ __launch_bounds__(256) void k_rbuild(
    const unsigned int* __restrict__ pairs, const int* __restrict__ S,
    int* __restrict__ row_ptr, int* __restrict__ col) {
    __shared__ int ncnt[512];
    __shared__ int nofs[512];
    __shared__ int part[256];
    int b = blockIdx.x;
    int t = threadIdx.x;
    int base = S[b * NCHUNK];
    int next = (b == NBKT - 1) ? S[FLAT] : S[(b + 1) * NCHUNK];
    int count = next - base;
    int nodeBase = b << BSH;

    ncnt[2 * t] = 0; ncnt[2 * t + 1] = 0;
    __syncthreads();
    for (int i = t; i < count; i += 256)
        atomicAdd(&ncnt[pairs[base + i] >> 17], 1);
    __syncthreads();
    // exclusive scan of ncnt[512]
    int v0 = ncnt[2 * t], v1 = ncnt[2 * t + 1];
    part[t] = v0 + v1;
    __syncthreads();
    for (int off = 1; off < 256; off <<= 1) {
        int add = (t >= off) ? part[t - off] : 0;
        __syncthreads();
        part[t] += add;
        __syncthreads();
    }
    int ex = (t > 0) ? part[t - 1] : 0;
    nofs[2 * t] = ex;
    nofs[2 * t + 1] = ex + v0;
    ncnt[2 * t] = 0; ncnt[2 * t + 1] = 0;
    __syncthreads();
    // row_ptr
    for (int i = t; i < 512; i += 256) {
        int node = nodeBase + i;
        if (node < N_NODES) row_ptr[node] = base + nofs[i];
    }
    if (b == 0 && t == 0) row_ptr[N_NODES] = N_EDGES;
    // col scatter (rank via LDS atomic; order within node irrelevant)
    for (int i = t; i < count; i += 256) {
        unsigned p = pairs[base + i];
        int li = p >> 17;
        int r = atomicAdd(&ncnt[li], 1);
        col[base + nofs[li] + r] = (int)(p & 0x1FFFFu);
    }
}

// ---------------------------------------------------------------------------
// FUSED SAGE layer: aggregate (quad-gather) + dense (MFMA), means in LDS.
// Block = 4 waves = 2 strips x 16 nodes. Per strip: 2 waves each aggregate
// 8 nodes into a transposed fp32 LDS tile amean[K][17] (pad 17 -> 2-way bank
// alias only); sync; each wave then computes 2 of the 4 output col-tiles,
// sourcing A-fragments from LDS (eliminates the global M round-trip:
// 2x25.6MB per layer). 3125 blocks = 12500 waves (R13 occupancy config).
// KM: mean K (gather stride). XBF: x-path from bf16 planes. OM: 1=hi+lo,
// 2=hi only (pre-pool layer).
// ---------------------------------------------------------------------------
template <int KM, bool XBF, int KX, int XS, int OM>
__global__ __launch_bounds__(256) void k_sage_fused(
    const unsigned short* __restrict__ ghb,   // gather source, bf16-hi, stride KM
    const float* x,                           // fp32 x-path (XBF=false)
    const unsigned short* xhi, const unsigned short* xlo,  // bf16 x-path
    const int* __restrict__ row_ptr, const int* __restrict__ col,
    const float* __restrict__ Wl, const float* __restrict__ bl,
    const float* __restrict__ Wr,
    unsigned short* ohi, unsigned short* olo) {
    __shared__ float amean[2][KM][17];

    int lane = threadIdx.x & 63;
    int wid  = threadIdx.x >> 6;
    int sl   = wid >> 1;            // strip-in-block (0,1)
    int half = wid & 1;             // 8-node half / col-tile half
    int strip = blockIdx.x * 2 + sl;
    int row0 = strip * 16;          // all strips full: 100000 = 3125*32

    // ================= phase A: aggregate 8 nodes -> LDS =================
    {
        constexpr int G = (KM == 64) ? 4 : 8;
        constexpr int LPR = 64 / G;
        int g  = lane / LPR;
        int fq = lane % LPR;
        int nodeBase = row0 + half * 8;
        int rp = row_ptr[nodeBase + (lane < 8 ? lane : 8)];

        for (int i = 0; i < 8; ++i) {
            int start = __shfl(rp, i);
            int end   = __shfl(rp, i + 1);
            float s0 = 0.0f, s1 = 0.0f, s2 = 0.0f, s3 = 0.0f;

            for (int eb = start; eb < end; eb += 64) {
                int n = end - eb; if (n > 64) n = 64;
                int c = (eb + lane < end) ? col[eb + lane] : 0;
                int j = 0;
                for (; j + 4 * G - 1 < n; j += 4 * G) {
                    int cA = __shfl(c, j + g);
                    int cB = __shfl(c, j + G + g);
                    int cC = __shfl(c, j + 2 * G + g);
                    int cD = __shfl(c, j + 3 * G + g);
                    ushort4 vA = *(const ushort4*)(ghb + (size_t)cA * KM + fq * 4);
                    ushort4 vB = *(const ushort4*)(ghb + (size_t)cB * KM + fq * 4);
                    ushort4 vC = *(const ushort4*)(ghb + (size_t)cC * KM + fq * 4);
                    ushort4 vD = *(const ushort4*)(ghb + (size_t)cD * KM + fq * 4);
                    s0 += (bf2f(vA.x) + bf2f(vB.x)) + (bf2f(vC.x) + bf2f(vD.x));
                    s1 += (bf2f(vA.y) + bf2f(vB.y)) + (bf2f(vC.y) + bf2f(vD.y));
                    s2 += (bf2f(vA.z) + bf2f(vB.z)) + (bf2f(vC.z) + bf2f(vD.z));
                    s3 += (bf2f(vA.w) + bf2f(vB.w)) + (bf2f(vC.w) + bf2f(vD.w));
                }
                for (; j + 2 * G - 1 < n; j += 2 * G) {
                    int cA = __shfl(c, j + g);
                    int cB = __shfl(c, j + G + g);
                    ushort4 vA = *(const ushort4*)(ghb + (size_t)cA * KM + fq * 4);
                    ushort4 vB = *(const ushort4*)(ghb + (size_t)cB * KM + fq * 4);
                    s0 += bf2f(vA.x) + bf2f(vB.x);
                    s1 += bf2f(vA.y) + bf2f(vB.y);
                    s2 += bf2f(vA.z) + bf2f(vB.z);
                    s3 += bf2f(vA.w) + bf2f(vB.w);
                }
                for (; j + G - 1 < n; j += G) {
                    int cA = __shfl(c, j + g);
                    ushort4 vA = *(const ushort4*)(ghb + (size_t)cA * KM + fq * 4);
                    s0 += bf2f(vA.x);
                    s1 += bf2f(vA.y);
                    s2 += bf2f(vA.z);
                    s3 += bf2f(vA.w);
                }
                if (j < n) {
                    int idx = j + g;
                    bool valid = idx < n;
                    int cA = __shfl(c, valid ? idx : 0);
                    ushort4 vA = *(const ushort4*)(ghb + (size_t)cA * KM + fq * 4);
                    if (valid) {
                        s0 += bf2f(vA.x);
                        s1 += bf2f(vA.y);
                        s2 += bf2f(vA.z);
                        s3 += bf2f(vA.w);
                    }
                }
            }
#pragma unroll
            for (int m = LPR; m < 64; m <<= 1) {
                s0 += __shfl_xor(s0, m);
                s1 += __shfl_xor(s1, m);
                s2 += __shfl_xor(s2, m);
                s3 += __shfl_xor(s3, m);
            }
            int deg = end - start;
            float inv = (deg > 0) ? 1.0f / (float)deg : 0.0f;
            if (lane < LPR) {
                int lr = half * 8 + i;            // local row in strip
                amean[sl][fq * 4 + 0][lr] = s0 * inv;
                amean[sl][fq * 4 + 1][lr] = s1 * inv;
                amean[sl][fq * 4 + 2][lr] = s2 * inv;
                amean[sl][fq * 4 + 3][lr] = s3 * inv;
            }
        }
    }
    __syncthreads();

    // ================= phase B: dense MFMA (2 col-tiles per wave) =========
    int m = lane & 15;
    int g = lane >> 4;
    f32x4 acc[2] = {};

    // ---- mean @ Wl (A from LDS, fp32 -> hi/lo split) ----
#pragma unroll
    for (int kt = 0; kt < KM / 32; ++kt) {
        int k0 = kt * 32 + g * 8;
        bf16x8 ahi, alo;
#pragma unroll
        for (int j = 0; j < 8; ++j) {
            float v = amean[sl][k0 + j][m];
            unsigned short hb = f2bf(v);
            ahi[j] = (short)hb;
            alo[j] = (short)f2bf(v - bf2f(hb));
        }
#pragma unroll
        for (int nti = 0; nti < 2; ++nti) {
            int nt = half * 2 + nti;
            bf16x8 b;
#pragma unroll
            for (int j = 0; j < 8; ++j)
                b[j] = (short)f2bf(Wl[(size_t)(k0 + j) * 64 + nt * 16 + m]);
            acc[nti] = __builtin_amdgcn_mfma_f32_16x16x32_bf16(ahi, b, acc[nti], 0, 0, 0);
            acc[nti] = __builtin_amdgcn_mfma_f32_16x16x32_bf16(alo, b, acc[nti], 0, 0, 0);
        }
    }
    // ---- h @ Wr ----
#pragma unroll
    for (int kt = 0; kt < KX / 32; ++kt) {
        int k0 = kt * 32 + g * 8;
        bf16x8 ahi, alo;
        if constexpr (XBF) {
            ahi = *(const bf16x8*)(xhi + (size_t)(row0 + m) * XS + k0);
            alo = *(const bf16x8*)(xlo + (size_t)(row0 + m) * XS + k0);
        } else {
            const float4* ap = (const float4*)(x + (size_t)(row0 + m) * XS + k0);
            float4 a0 = ap[0], a1 = ap[1];
            float av[8] = {a0.x, a0.y, a0.z, a0.w, a1.x, a1.y, a1.z, a1.w};
#pragma unroll
            for (int j = 0; j < 8; ++j) {
                unsigned short hb = f2bf(av[j]);
                ahi[j] = (short)hb;
                alo[j] = (short)f2bf(av[j] - bf2f(hb));
            }
        }
#pragma unroll
        for (int nti = 0; nti < 2; ++nti) {
            int nt = half * 2 + nti;
            bf16x8 b;
#pragma unroll
            for (int j = 0; j < 8; ++j)
                b[j] = (short)f2bf(Wr[(size_t)(k0 + j) * 64 + nt * 16 + m]);
            acc[nti] = __builtin_amdgcn_mfma_f32_16x16x32_bf16(ahi, b, acc[nti], 0, 0, 0);
            acc[nti] = __builtin_amdgcn_mfma_f32_16x16x32_bf16(alo, b, acc[nti], 0, 0, 0);
        }
    }
    // ---- bias + store ----
#pragma unroll
    for (int nti = 0; nti < 2; ++nti) {
        int nt = half * 2 + nti;
        float bias = bl[nt * 16 + m];
#pragma unroll
        for (int r = 0; r < 4; ++r) {
            int row = row0 + g * 4 + r;
            float v = acc[nti][r] + bias;
            if constexpr (OM == 1) {
                unsigned short hb = f2bf(v);
                ohi[(size_t)row * 64 + nt * 16 + m] = hb;
                olo[(size_t)row * 64 + nt * 16 + m] = f2bf(v - bf2f(hb));
            } else {
                ohi[(size_t)row * 64 + nt * 16 + m] = f2bf(v);
            }
        }
    }
}

// ---- segment-parallel max pool over the bf16 hi plane ----
#define PSPLIT 8
__global__ __launch_bounds__(256) void k_pool2(const unsigned short* __restrict__ h,
                                               const int* __restrict__ gstart,
                                               float* __restrict__ pooled) {
    __shared__ float red[4][64];
    int gr = blockIdx.x & 63;
    int split = blockIdx.x >> 6;
    int lane = threadIdx.x & 63;
    int w = threadIdx.x >> 6;
    int s = gstart[gr], e = gstart[gr + 1];
    float m = -INFINITY;
    for (int i = s + split * 4 + w; i < e; i += PSPLIT * 4)
        m = fmaxf(m, bf2f(h[(size_t)i * 64 + lane]));
    red[w][lane] = m;
    __syncthreads();
    if (w == 0) {
        m = fmaxf(fmaxf(red[0][lane], red[1][lane]),
                  fmaxf(red[2][lane], red[3][lane]));
        if (m > -INFINITY) atomicMaxFloat(&pooled[gr * 64 + lane], m);
    }
}

__global__ void k_head(const float* __restrict__ pooled,
                       const float* __restrict__ Wout,
                       const float* __restrict__ bout, float* __restrict__ out) {
    int tid = threadIdx.x;          // 512 threads: g = tid>>3, o = tid&7
    int g = tid >> 3, o = tid & 7;
    float acc = bout[o];
#pragma unroll
    for (int k = 0; k < 64; ++k) acc += pooled[g * 64 + k] * Wout[k * 8 + o];
    float mx = acc;
#pragma unroll
    for (int m = 1; m < 8; m <<= 1) mx = fmaxf(mx, __shfl_xor(mx, m));
    float ex = expf(acc - mx);
    float sum = ex;
#pragma unroll
    for (int m = 1; m < 8; m <<= 1) sum += __shfl_xor(sum, m);
    out[g * 8 + o] = (acc - mx) - logf(sum);
}

extern "C" void kernel_launch(void* const* d_in, const int* in_sizes, int n_in,
                              void* d_out, int out_size, void* d_ws, size_t ws_size,
                              hipStream_t stream) {
    const float* x    = (const float*)d_in[0];
    const float* Wl0  = (const float*)d_in[1];
    const float* bl0  = (const float*)d_in[2];
    const float* Wr0  = (const float*)d_in[3];
    const float* Wl1  = (const float*)d_in[4];
    const float* bl1  = (const float*)d_in[5];
    const float* Wr1  = (const float*)d_in[6];
    const float* Wl2  = (const float*)d_in[7];
    const float* bl2  = (const float*)d_in[8];
    const float* Wr2  = (const float*)d_in[9];
    const float* Wout = (const float*)d_in[10];
    const float* bout = (const float*)d_in[11];
    const int*   eidx = (const int*)d_in[12];
    const int*   batch= (const int*)d_in[13];
    const int* src = eidx;
    const int* dst = eidx + N_EDGES;

    uint8_t* ws = (uint8_t*)d_ws;
    int*   S       = (int*)(ws + 0);                // 50177 ints
    int*   row_ptr = (int*)(ws + 400128);
    int*   col     = (int*)(ws + 800256);
    float* pooled  = (float*)(ws + 7200384);
    int*   gstart  = (int*)(ws + 7216768);
    unsigned short* H1hi = (unsigned short*)(ws + 7217408);
    unsigned short* H1lo = (unsigned short*)(ws + 20017408);
    unsigned short* H2hi = (unsigned short*)(ws + 32817408);
    unsigned short* H2lo = (unsigned short*)(ws + 45617408);
    unsigned int* pairs  = (unsigned int*)(ws + 32817408);  // aliases H2hi (dead after rbuild)
    unsigned short* Xhi  = (unsigned short*)(ws + 45617408); // aliases H2lo (dead after layer 0)

    k_prep<<<(N_NODES * 32 / 8 + 255) / 256, 256, 0, stream>>>(
        x, Xhi, batch, gstart, pooled);
    k_rhist<<<NCHUNK, 256, 0, stream>>>(dst, S);
    k_rscan<<<1, 1024, 0, stream>>>(S);
    k_rscatter<<<NCHUNK, 256, 0, stream>>>(src, dst, S, pairs);
    k_rbuild<<<NBKT, 256, 0, stream>>>(pairs, S, row_ptr, col);

    int fusedBlocks = N_NODES / 32;   // 3125: 2 strips of 16 nodes per block

    // layer 0: gather Xhi (stride 32) + x fp32 path -> H1hi/H1lo
    k_sage_fused<32, false, 32, 32, 1><<<fusedBlocks, 256, 0, stream>>>(
        Xhi, x, nullptr, nullptr, row_ptr, col, Wl0, bl0, Wr0, H1hi, H1lo);
    // layer 1: gather H1hi + H1 bf16 path -> H2hi/H2lo (overwrites pairs/Xhi: dead)
    k_sage_fused<64, true, 64, 64, 1><<<fusedBlocks, 256, 0, stream>>>(
        H1hi, nullptr, H1hi, H1lo, row_ptr, col, Wl1, bl1, Wr1, H2hi, H2lo);
    // layer 2: gather H2hi + H2 bf16 path -> H1hi (hi only); pool reads H1hi
    k_sage_fused<64, true, 64, 64, 2><<<fusedBlocks, 256, 0, stream>>>(
        H2hi, nullptr, H2hi, H2lo, row_ptr, col, Wl2, bl2, Wr2, H1hi, nullptr);

    k_pool2<<<64 * PSPLIT, 256, 0, stream>>>(H1hi, gstart, pooled);
    k_head<<<1, 512, 0, stream>>>(pooled, Wout, bout, (float*)d_out);
}

// Round 16
// 222.628 us; speedup vs baseline: 1.2941x; 1.0708x over previous
//
#include <hip/hip_runtime.h>
#include <math.h>
#include <stdint.h>

#define N_NODES 100000
#define N_EDGES 1600000
#define N_GRAPHS 64

// ---- atomic-free CSR build geometry ----
#define BSH 9                  // bucket width = 512 nodes
#define NBKT 196               // ceil(100000/512)
#define NCHUNK 256
#define EPC 6250               // N_EDGES / NCHUNK
#define FLAT (NBKT * NCHUNK)   // 50176

// ---------------- workspace layout (bytes) ----------------
// S(histMat)@ 0      : 50177 int (200708 B)
// WT (bf16 weights, transposed [col][k]) @ 204800 : 20480 ushort (40960 B)
// row_ptr @ 400128   : 100001 int
// col     @ 800256   : 1600000 int (6.4 MB)
// pooled  @ 7200384  : 64*64 float
// gstart  @ 7216768  : 65 int
// H1hi    @ 7217408  : 100000*64 bf16 (12.8 MB)
// H1lo    @ 20017408 : 100000*64 bf16 (12.8 MB)
// H2hi    @ 32817408 : 100000*64 bf16 (12.8 MB)   [pairs 6.4MB aliases]
// H2lo    @ 45617408 : 100000*64 bf16 (12.8 MB)   [Xhi 6.4MB aliases]
// total ~58.4 MB

typedef __attribute__((ext_vector_type(8))) short bf16x8;
typedef __attribute__((ext_vector_type(8))) unsigned short u16x8;
typedef __attribute__((ext_vector_type(4))) float f32x4;

// WT element offsets: [0]=Wl0(2048) [2048]=Wr0 [4096]=Wl1(4096) [8192]=Wr1
// [12288]=Wl2 [16384]=Wr2 ; total 20480 elements
#define WT0L 0
#define WT0R 2048
#define WT1L 4096
#define WT1R 8192
#define WT2L 12288
#define WT2R 16384

__device__ __forceinline__ void atomicMaxFloat(float* addr, float val) {
    if (val >= 0.0f) {
        atomicMax((int*)addr, __float_as_int(val));
    } else {
        atomicMin((unsigned int*)addr, __float_as_uint(val));
    }
}

__device__ __forceinline__ unsigned short f2bf(float f) {   // RNE fp32 -> bf16
    unsigned u = __float_as_uint(f);
    unsigned r = (u + 0x7FFFu + ((u >> 16) & 1u)) >> 16;
    return (unsigned short)r;
}
__device__ __forceinline__ float bf2f(unsigned short b) {
    return __uint_as_float(((unsigned)b) << 16);
}

// ---- fused prep: xcast + gbound + pooled init + weight cast/transpose +
//      rhist (blocks < NCHUNK histogram their edge chunk; block-uniform) ----
__global__ __launch_bounds__(256) void k_prep(
    const float* __restrict__ x, unsigned short* __restrict__ xhi,
    const int* __restrict__ batch, int* __restrict__ gstart,
    float* __restrict__ pooled,
    const float* __restrict__ Wl0, const float* __restrict__ Wr0,
    const float* __restrict__ Wl1, const float* __restrict__ Wr1,
    const float* __restrict__ Wl2, const float* __restrict__ Wr2,
    unsigned short* __restrict__ WT,
    const int* __restrict__ dst, int* __restrict__ S) {
    __shared__ int h[NBKT];
    int i = blockIdx.x * blockDim.x + threadIdx.x;

    if (i < N_NODES * 32 / 8) {
        int base = i * 8;
        const float4* xp = (const float4*)(x + base);
        float4 a = xp[0], b = xp[1];
        u16x8 o;
        o[0] = f2bf(a.x); o[1] = f2bf(a.y); o[2] = f2bf(a.z); o[3] = f2bf(a.w);
        o[4] = f2bf(b.x); o[5] = f2bf(b.y); o[6] = f2bf(b.z); o[7] = f2bf(b.w);
        *(u16x8*)(xhi + base) = o;
    }
    if (i < N_GRAPHS * 64) pooled[i] = -INFINITY;
    if (i < N_NODES) {
        int b = batch[i];
        if (i == 0) {
            for (int g = 0; g <= b; ++g) gstart[g] = 0;
        } else {
            int pb = batch[i - 1];
            for (int g = pb + 1; g <= b; ++g) gstart[g] = i;
        }
        if (i == N_NODES - 1) {
            for (int g = b + 1; g <= N_GRAPHS; ++g) gstart[g] = N_NODES;
        }
    }
    // weight cast + transpose: WT[col][k] = bf16(W[k][col]); 8 el/thread
    if (i < 2560) {
        const float* Wsrc; int wofs, KW, local;
        if (i < 256)       { Wsrc = Wl0; wofs = WT0L; KW = 32; local = i; }
        else if (i < 512)  { Wsrc = Wr0; wofs = WT0R; KW = 32; local = i - 256; }
        else if (i < 1024) { Wsrc = Wl1; wofs = WT1L; KW = 64; local = i - 512; }
        else if (i < 1536) { Wsrc = Wr1; wofs = WT1R; KW = 64; local = i - 1024; }
        else if (i < 2048) { Wsrc = Wl2; wofs = WT2L; KW = 64; local = i - 1536; }
        else               { Wsrc = Wr2; wofs = WT2R; KW = 64; local = i - 2048; }
        int e = local * 8;
        int colw = e / KW, k0 = e % KW;
        u16x8 o;
#pragma unroll
        for (int j = 0; j < 8; ++j) o[j] = f2bf(Wsrc[(size_t)(k0 + j) * 64 + colw]);
        *(u16x8*)(WT + wofs + e) = o;
    }
    // rhist for blocks < NCHUNK (block-uniform control flow around barriers)
    if (blockIdx.x < NCHUNK) {
        for (int q = threadIdx.x; q < NBKT; q += 256) h[q] = 0;
        __syncthreads();
        int c = blockIdx.x;
        int e0 = c * EPC;
        for (int e = e0 + threadIdx.x; e < e0 + EPC; e += 256)
            atomicAdd(&h[dst[e] >> BSH], 1);
        __syncthreads();
        for (int q = threadIdx.x; q < NBKT; q += 256) S[q * NCHUNK + c] = h[q];
    }
}

// ---- CSR phase 2: exclusive scan of S[0..FLAT) in place; S[FLAT]=total ----
__global__ __launch_bounds__(1024) void k_rscan(int* __restrict__ S) {
    __shared__ int part[1024];
    int t = threadIdx.x;
    const int seg = (FLAT + 1023) / 1024;   // 49
    int lo = t * seg;
    int hi = lo + seg; if (hi > FLAT) hi = FLAT;
    int s = 0;
    for (int i = lo; i < hi; ++i) s += S[i];
    part[t] = s;
    __syncthreads();
    for (int off = 1; off < 1024; off <<= 1) {
        int add = (t >= off) ? part[t - off] : 0;
        __syncthreads();
        part[t] += add;
        __syncthreads();
    }
    int ex = (t > 0) ? part[t - 1] : 0;
    if (t == 1023) S[FLAT] = part[1023];
    int run = ex;
    for (int i = lo; i < hi; ++i) { int v = S[i]; S[i] = run; run += v; }
}

// ---- CSR phase 3: scatter packed (dstLocal:9 | src:17) bucket-grouped ----
__global__ __launch_bounds__(256) void k_rscatter(
    const int* __restrict__ src, const int* __restrict__ dst,
    const int* __restrict__ S, unsigned int* __restrict__ pairs) {
    __shared__ int ofs[NBKT];
    __shared__ int cnt[NBKT];
    int c = blockIdx.x;
    for (int i = threadIdx.x; i < NBKT; i += 256) {
        ofs[i] = S[i * NCHUNK + c];
        cnt[i] = 0;
    }
    __syncthreads();
    int e0 = c * EPC;
    for (int e = e0 + threadIdx.x; e < e0 + EPC; e += 256) {
        int d = dst[e];
        int b = d >> BSH;
        int r = atomicAdd(&cnt[b], 1);           // LDS atomic
        pairs[ofs[b] + r] = ((unsigned)(d & 511) << 17) | (unsigned)src[e];
    }
}

// ---- CSR phase 4: per bucket, build row_ptr + col (all LDS-local) ----
__global__ __launch_bounds__(256) void k_rbuild(
    const unsigned int* __restrict__ pairs, const int* __restrict__ S,
    int* __restrict__ row_ptr, int* __restrict__ col) {
    __shared__ int ncnt[512];
    __shared__ int nofs[512];
    __shared__ int part[256];
    int b = blockIdx.x;
    int t = threadIdx.x;
    int base = S[b * NCHUNK];
    int next = (b == NBKT - 1) ? S[FLAT] : S[(b + 1) * NCHUNK];
    int count = next - base;
    int nodeBase = b << BSH;

    ncnt[2 * t] = 0; ncnt[2 * t + 1] = 0;
    __syncthreads();
    for (int i = t; i < count; i += 256)
        atomicAdd(&ncnt[pairs[base + i] >> 17], 1);
    __syncthreads();
    // exclusive scan of ncnt[512]
    int v0 = ncnt[2 * t], v1 = ncnt[2 * t + 1];
    part[t] = v0 + v1;
    __syncthreads();
    for (int off = 1; off < 256; off <<= 1) {
        int add = (t >= off) ? part[t - off] : 0;
        __syncthreads();
        part[t] += add;
        __syncthreads();
    }
    int ex = (t > 0) ? part[t - 1] : 0;
    nofs[2 * t] = ex;
    nofs[2 * t + 1] = ex + v0;
    ncnt[2 * t] = 0; ncnt[2 * t + 1] = 0;
    __syncthreads();
    // row_ptr
    for (int i = t; i < 512; i += 256) {
        int node = nodeBase + i;
        if (node < N_NODES) row_ptr[node] = base + nofs[i];
    }
    if (b == 0 && t == 0) row_ptr[N_NODES] = N_EDGES;
    // col scatter (rank via LDS atomic; order within node irrelevant)
    for (int i = t; i < count; i += 256) {
        unsigned p = pairs[base + i];
        int li = p >> 17;
        int r = atomicAdd(&ncnt[li], 1);
        col[base + nofs[li] + r] = (int)(p & 0x1FFFFu);
    }
}

// ---------------------------------------------------------------------------
// FUSED SAGE layer: aggregate (quad-gather) + dense (MFMA), means in LDS.
// R16: (a) weights pre-transposed bf16 -> B fragment is ONE 16B load;
// (b) amean node-major [2][16][KM+4] -> ds_write_b128 / ds_read_b128.
// Block = 4 waves = 2 strips x 16 nodes.
// ---------------------------------------------------------------------------
template <int KM, bool XBF, int KX, int XS, int OM>
__global__ __launch_bounds__(256) void k_sage_fused(
    const unsigned short* __restrict__ ghb,   // gather source, bf16-hi, stride KM
    const float* x,                           // fp32 x-path (XBF=false)
    const unsigned short* xhi, const unsigned short* xlo,  // bf16 x-path
    const int* __restrict__ row_ptr, const int* __restrict__ col,
    const unsigned short* __restrict__ WTl,   // bf16 [col][KM]
    const float* __restrict__ bl,
    const unsigned short* __restrict__ WTr,   // bf16 [col][KX]
    unsigned short* ohi, unsigned short* olo) {
    __shared__ float amean[2][16][KM + 4];

    int lane = threadIdx.x & 63;
    int wid  = threadIdx.x >> 6;
    int sl   = wid >> 1;            // strip-in-block (0,1)
    int half = wid & 1;             // 8-node half / col-tile half
    int strip = blockIdx.x * 2 + sl;
    int row0 = strip * 16;          // all strips full: 100000 = 3125*32

    // ================= phase A: aggregate 8 nodes -> LDS =================
    {
        constexpr int G = (KM == 64) ? 4 : 8;
        constexpr int LPR = 64 / G;
        int g  = lane / LPR;
        int fq = lane % LPR;
        int nodeBase = row0 + half * 8;
        int rp = row_ptr[nodeBase + (lane < 8 ? lane : 8)];

        for (int i = 0; i < 8; ++i) {
            int start = __shfl(rp, i);
            int end   = __shfl(rp, i + 1);
            float s0 = 0.0f, s1 = 0.0f, s2 = 0.0f, s3 = 0.0f;

            for (int eb = start; eb < end; eb += 64) {
                int n = end - eb; if (n > 64) n = 64;
                int c = (eb + lane < end) ? col[eb + lane] : 0;
                int j = 0;
                for (; j + 4 * G - 1 < n; j += 4 * G) {
                    int cA = __shfl(c, j + g);
                    int cB = __shfl(c, j + G + g);
                    int cC = __shfl(c, j + 2 * G + g);
                    int cD = __shfl(c, j + 3 * G + g);
                    ushort4 vA = *(const ushort4*)(ghb + (size_t)cA * KM + fq * 4);
                    ushort4 vB = *(const ushort4*)(ghb + (size_t)cB * KM + fq * 4);
                    ushort4 vC = *(const ushort4*)(ghb + (size_t)cC * KM + fq * 4);
                    ushort4 vD = *(const ushort4*)(ghb + (size_t)cD * KM + fq * 4);
                    s0 += (bf2f(vA.x) + bf2f(vB.x)) + (bf2f(vC.x) + bf2f(vD.x));
                    s1 += (bf2f(vA.y) + bf2f(vB.y)) + (bf2f(vC.y) + bf2f(vD.y));
                    s2 += (bf2f(vA.z) + bf2f(vB.z)) + (bf2f(vC.z) + bf2f(vD.z));
                    s3 += (bf2f(vA.w) + bf2f(vB.w)) + (bf2f(vC.w) + bf2f(vD.w));
                }
                for (; j + 2 * G - 1 < n; j += 2 * G) {
                    int cA = __shfl(c, j + g);
                    int cB = __shfl(c, j + G + g);
                    ushort4 vA = *(const ushort4*)(ghb + (size_t)cA * KM + fq * 4);
                    ushort4 vB = *(const ushort4*)(ghb + (size_t)cB * KM + fq * 4);
                    s0 += bf2f(vA.x) + bf2f(vB.x);
                    s1 += bf2f(vA.y) + bf2f(vB.y);
                    s2 += bf2f(vA.z) + bf2f(vB.z);
                    s3 += bf2f(vA.w) + bf2f(vB.w);
                }
                for (; j + G - 1 < n; j += G) {
                    int cA = __shfl(c, j + g);
                    ushort4 vA = *(const ushort4*)(ghb + (size_t)cA * KM + fq * 4);
                    s0 += bf2f(vA.x);
                    s1 += bf2f(vA.y);
                    s2 += bf2f(vA.z);
                    s3 += bf2f(vA.w);
                }
                if (j < n) {
                    int idx = j + g;
                    bool valid = idx < n;
                    int cA = __shfl(c, valid ? idx : 0);
                    ushort4 vA = *(const ushort4*)(ghb + (size_t)cA * KM + fq * 4);
                    if (valid) {
                        s0 += bf2f(vA.x);
                        s1 += bf2f(vA.y);
                        s2 += bf2f(vA.z);
                        s3 += bf2f(vA.w);
                    }
                }
            }
#pragma unroll
            for (int m = LPR; m < 64; m <<= 1) {
                s0 += __shfl_xor(s0, m);
                s1 += __shfl_xor(s1, m);
                s2 += __shfl_xor(s2, m);
                s3 += __shfl_xor(s3, m);
            }
            int deg = end - start;
            float inv = (deg > 0) ? 1.0f / (float)deg : 0.0f;
            if (lane < LPR) {
                int lr = half * 8 + i;            // local row in strip
                *(float4*)&amean[sl][lr][fq * 4] =
                    make_float4(s0 * inv, s1 * inv, s2 * inv, s3 * inv);
            }
        }
    }
    __syncthreads();

    // ================= phase B: dense MFMA (2 col-tiles per wave) =========
    int m = lane & 15;
    int g = lane >> 4;
    f32x4 acc[2] = {};

    // ---- mean @ Wl (A from LDS float4 pair, fp32 -> hi/lo split) ----
#pragma unroll
    for (int kt = 0; kt < KM / 32; ++kt) {
        int k0 = kt * 32 + g * 8;
        const float* ar = &amean[sl][m][k0];
        float4 a0 = *(const float4*)(ar);
        float4 a1 = *(const float4*)(ar + 4);
        float av[8] = {a0.x, a0.y, a0.z, a0.w, a1.x, a1.y, a1.z, a1.w};
        bf16x8 ahi, alo;
#pragma unroll
        for (int j = 0; j < 8; ++j) {
            unsigned short hb = f2bf(av[j]);
            ahi[j] = (short)hb;
            alo[j] = (short)f2bf(av[j] - bf2f(hb));
        }
#pragma unroll
        for (int nti = 0; nti < 2; ++nti) {
            int nt = half * 2 + nti;
            bf16x8 b = *(const bf16x8*)(WTl + (size_t)(nt * 16 + m) * KM + k0);
            acc[nti] = __builtin_amdgcn_mfma_f32_16x16x32_bf16(ahi, b, acc[nti], 0, 0, 0);
            acc[nti] = __builtin_amdgcn_mfma_f32_16x16x32_bf16(alo, b, acc[nti], 0, 0, 0);
        }
    }
    // ---- h @ Wr ----
#pragma unroll
    for (int kt = 0; kt < KX / 32; ++kt) {
        int k0 = kt * 32 + g * 8;
        bf16x8 ahi, alo;
        if constexpr (XBF) {
            ahi = *(const bf16x8*)(xhi + (size_t)(row0 + m) * XS + k0);
            alo = *(const bf16x8*)(xlo + (size_t)(row0 + m) * XS + k0);
        } else {
            const float4* ap = (const float4*)(x + (size_t)(row0 + m) * XS + k0);
            float4 a0 = ap[0], a1 = ap[1];
            float av[8] = {a0.x, a0.y, a0.z, a0.w, a1.x, a1.y, a1.z, a1.w};
#pragma unroll
            for (int j = 0; j < 8; ++j) {
                unsigned short hb = f2bf(av[j]);
                ahi[j] = (short)hb;
                alo[j] = (short)f2bf(av[j] - bf2f(hb));
            }
        }
#pragma unroll
        for (int nti = 0; nti < 2; ++nti) {
            int nt = half * 2 + nti;
            bf16x8 b = *(const bf16x8*)(WTr + (size_t)(nt * 16 + m) * KX + k0);
            acc[nti] = __builtin_amdgcn_mfma_f32_16x16x32_bf16(ahi, b, acc[nti], 0, 0, 0);
            acc[nti] = __builtin_amdgcn_mfma_f32_16x16x32_bf16(alo, b, acc[nti], 0, 0, 0);
        }
    }
    // ---- bias + store ----
#pragma unroll
    for (int nti = 0; nti < 2; ++nti) {
        int nt = half * 2 + nti;
        float bias = bl[nt * 16 + m];
#pragma unroll
        for (int r = 0; r < 4; ++r) {
            int row = row0 + g * 4 + r;
            float v = acc[nti][r] + bias;
            if constexpr (OM == 1) {
                unsigned short hb = f2bf(v);
                ohi[(size_t)row * 64 + nt * 16 + m] = hb;
                olo[(size_t)row * 64 + nt * 16 + m] = f2bf(v - bf2f(hb));
            } else {
                ohi[(size_t)row * 64 + nt * 16 + m] = f2bf(v);
            }
        }
    }
}

// ---- segment-parallel max pool over the bf16 hi plane ----
#define PSPLIT 8
__global__ __launch_bounds__(256) void k_pool2(const unsigned short* __restrict__ h,
                                               const int* __restrict__ gstart,
                                               float* __restrict__ pooled) {
    __shared__ float red[4][64];
    int gr = blockIdx.x & 63;
    int split = blockIdx.x >> 6;
    int lane = threadIdx.x & 63;
    int w = threadIdx.x >> 6;
    int s = gstart[gr], e = gstart[gr + 1];
    float m = -INFINITY;
    for (int i = s + split * 4 + w; i < e; i += PSPLIT * 4)
        m = fmaxf(m, bf2f(h[(size_t)i * 64 + lane]));
    red[w][lane] = m;
    __syncthreads();
    if (w == 0) {
        m = fmaxf(fmaxf(red[0][lane], red[1][lane]),
                  fmaxf(red[2][lane], red[3][lane]));
        if (m > -INFINITY) atomicMaxFloat(&pooled[gr * 64 + lane], m);
    }
}

__global__ void k_head(const float* __restrict__ pooled,
                       const float* __restrict__ Wout,
                       const float* __restrict__ bout, float* __restrict__ out) {
    int tid = threadIdx.x;          // 512 threads: g = tid>>3, o = tid&7
    int g = tid >> 3, o = tid & 7;
    float acc = bout[o];
#pragma unroll
    for (int k = 0; k < 64; ++k) acc += pooled[g * 64 + k] * Wout[k * 8 + o];
    float mx = acc;
#pragma unroll
    for (int m = 1; m < 8; m <<= 1) mx = fmaxf(mx, __shfl_xor(mx, m));
    float ex = expf(acc - mx);
    float sum = ex;
#pragma unroll
    for (int m = 1; m < 8; m <<= 1) sum += __shfl_xor(sum, m);
    out[g * 8 + o] = (acc - mx) - logf(sum);
}

extern "C" void kernel_launch(void* const* d_in, const int* in_sizes, int n_in,
                              void* d_out, int out_size, void* d_ws, size_t ws_size,
                              hipStream_t stream) {
    const float* x    = (const float*)d_in[0];
    const float* Wl0  = (const float*)d_in[1];
    const float* bl0  = (const float*)d_in[2];
    const float* Wr0  = (const float*)d_in[3];
    const float* Wl1  = (const float*)d_in[4];
    const float* bl1  = (const float*)d_in[5];
    const float* Wr1  = (const float*)d_in[6];
    const float* Wl2  = (const float*)d_in[7];
    const float* bl2  = (const float*)d_in[8];
    const float* Wr2  = (const float*)d_in[9];
    const float* Wout = (const float*)d_in[10];
    const float* bout = (const float*)d_in[11];
    const int*   eidx = (const int*)d_in[12];
    const int*   batch= (const int*)d_in[13];
    const int* src = eidx;
    const int* dst = eidx + N_EDGES;

    uint8_t* ws = (uint8_t*)d_ws;
    int*   S       = (int*)(ws + 0);                      // 50177 ints
    unsigned short* WT = (unsigned short*)(ws + 204800);  // 20480 ushort
    int*   row_ptr = (int*)(ws + 400128);
    int*   col     = (int*)(ws + 800256);
    float* pooled  = (float*)(ws + 7200384);
    int*   gstart  = (int*)(ws + 7216768);
    unsigned short* H1hi = (unsigned short*)(ws + 7217408);
    unsigned short* H1lo = (unsigned short*)(ws + 20017408);
    unsigned short* H2hi = (unsigned short*)(ws + 32817408);
    unsigned short* H2lo = (unsigned short*)(ws + 45617408);
    unsigned int* pairs  = (unsigned int*)(ws + 32817408);  // aliases H2hi
    unsigned short* Xhi  = (unsigned short*)(ws + 45617408); // aliases H2lo

    k_prep<<<(N_NODES * 32 / 8 + 255) / 256, 256, 0, stream>>>(
        x, Xhi, batch, gstart, pooled,
        Wl0, Wr0, Wl1, Wr1, Wl2, Wr2, WT, dst, S);
    k_rscan<<<1, 1024, 0, stream>>>(S);
    k_rscatter<<<NCHUNK, 256, 0, stream>>>(src, dst, S, pairs);
    k_rbuild<<<NBKT, 256, 0, stream>>>(pairs, S, row_ptr, col);

    int fusedBlocks = N_NODES / 32;   // 3125: 2 strips of 16 nodes per block

    // layer 0: gather Xhi (stride 32) + x fp32 path -> H1hi/H1lo
    k_sage_fused<32, false, 32, 32, 1><<<fusedBlocks, 256, 0, stream>>>(
        Xhi, x, nullptr, nullptr, row_ptr, col,
        WT + WT0L, bl0, WT + WT0R, H1hi, H1lo);
    // layer 1: gather H1hi + H1 bf16 path -> H2hi/H2lo (overwrites pairs/Xhi)
    k_sage_fused<64, true, 64, 64, 1><<<fusedBlocks, 256, 0, stream>>>(
        H1hi, nullptr, H1hi, H1lo, row_ptr, col,
        WT + WT1L, bl1, WT + WT1R, H2hi, H2lo);
    // layer 2: gather H2hi + H2 bf16 path -> H1hi (hi only); pool reads H1hi
    k_sage_fused<64, true, 64, 64, 2><<<fusedBlocks, 256, 0, stream>>>(
        H2hi, nullptr, H2hi, H2lo, row_ptr, col,
        WT + WT2L, bl2, WT + WT2R, H1hi, nullptr);

    k_pool2<<<64 * PSPLIT, 256, 0, stream>>>(H1hi, gstart, pooled);
    k_head<<<1, 512, 0, stream>>>(pooled, Wout, bout, (float*)d_out);
}